// Round 3
// baseline (9976.678 us; speedup 1.0000x reference)
//
#include <hip/hip_runtime.h>
#include <hip/hip_bf16.h>

#define B_   32
#define T_   512
#define E_   300
#define H_   256
#define OUT_ 256
#define NWG_ 128

// ---------------------------------------------------------------------------
// Slot tables: fslot[b][t] = index among True fmask positions (else -1)
//              bpos [b][t] = OUT-1-index among True bmask positions (else -1)
// Runtime-detects bool-byte vs int32 masks (exactly 256 True per row).
// ---------------------------------------------------------------------------
__global__ __launch_bounds__(64) void slots_kernel(
    const unsigned char* __restrict__ fm, const unsigned char* __restrict__ bm,
    int* __restrict__ fslot, int* __restrict__ bpos)
{
    int b = threadIdx.x;
    if (b >= B_) return;
    int cnt = 0;
    for (int t = 0; t < T_; ++t) cnt += (fm[b * T_ + t] != 0);
    bool isbool = (cnt == 256);
    const int* fmi = (const int*)fm;
    const int* bmi = (const int*)bm;
    int jf = 0, jb = 0;
    for (int t = 0; t < T_; ++t) {
        bool f = isbool ? (fm[b * T_ + t] != 0) : (fmi[b * T_ + t] != 0);
        bool g = isbool ? (bm[b * T_ + t] != 0) : (bmi[b * T_ + t] != 0);
        fslot[b * T_ + t] = f ? (jf++) : -1;
        bpos [b * T_ + t] = g ? (OUT_ - 1 - (jb++)) : -1;
    }
}

// ---------------------------------------------------------------------------
// Persistent bidirectional LSTM: 128 WGs (64 per dir, 4 hidden units each),
// one device-scope barrier per time step, xg(t+1) computed inside the
// barrier slack. h ping-pong in ws, stored transposed [e4][b] float4 so
// global loads and ds_read_b128 are contiguous per 32-lane group. c in regs.
// ---------------------------------------------------------------------------
__global__ __launch_bounds__(256) void persist_lstm(
    const int* __restrict__ inputs, const int* __restrict__ seqlen,
    const float* __restrict__ emb,
    const float* __restrict__ Wih_f, const float* __restrict__ Whh_f,
    const float* __restrict__ bih_f, const float* __restrict__ bhh_f,
    const float* __restrict__ Wih_b, const float* __restrict__ Whh_b,
    const float* __restrict__ bih_b, const float* __restrict__ bhh_b,
    const int* __restrict__ fslot, const int* __restrict__ bpos,
    float* __restrict__ hbuf, int* __restrict__ cntp, int* __restrict__ genp,
    float* __restrict__ out)
{
    const int wg  = blockIdx.x;          // 0..127
    const int dir = wg >> 6;
    const int u0  = (wg & 63) * 4;       // this WG's 4 hidden units
    const int tid = threadIdx.x;
    const int b31 = tid & 31;
    const int qg  = tid >> 5;            // 0..7

    __shared__ float hLT[64][32][4];     // h(t-1) transposed, 32 KB
    __shared__ float eLT[38][32][4];     // emb chunk transposed, 19 KB
    __shared__ float gbuf[16][33];       // gate exchange
    __shared__ int   sL[B_];

    const float* Wih = dir ? Wih_b : Wih_f;
    const float* Whh = dir ? Whh_b : Whh_f;
    const float* bi  = dir ? bih_b : bih_f;
    const float* bh  = dir ? bhh_b : bhh_f;

    // thread owns gate rows lr0 (gates i/f) and lr1 (gates g/o) of its WG slice
    const int lr0 = qg, lr1 = qg + 8;
    const int grow0 = (lr0 >> 2) * H_ + u0 + (lr0 & 3);
    const int grow1 = (lr1 >> 2) * H_ + u0 + (lr1 & 3);
    const float bias0 = bi[grow0] + bh[grow0];
    const float bias1 = bi[grow1] + bh[grow1];

    if (tid < B_) sL[tid] = seqlen[tid];
    __syncthreads();
    const int Lb = sL[b31];

    float xg0, xg1;

    // stage emb(tstep) transposed into eLT (two 19KB k-chunks) and dot W_ih
#define COMPUTE_XG(tstep)                                                      \
    {                                                                          \
        int tt = (tstep);                                                      \
        if (dir) tt = ((tstep) < Lb) ? (Lb - 1 - (tstep)) : (tstep);           \
        const float* erow = emb + (size_t)inputs[b31 * T_ + tt] * E_;          \
        float s0 = bias0, s1 = bias1;                                          \
        for (int e4 = qg; e4 < 38; e4 += 8)                                    \
            *(float4*)&eLT[e4][b31][0] = *(const float4*)(erow + e4 * 4);      \
        __syncthreads();                                                       \
        _Pragma("unroll 2")                                                    \
        for (int e4 = 0; e4 < 38; ++e4) {                                      \
            float4 h4 = *(const float4*)&eLT[e4][b31][0];                      \
            float4 w0 = *(const float4*)(Wih + (size_t)grow0 * E_ + e4 * 4);   \
            float4 w1 = *(const float4*)(Wih + (size_t)grow1 * E_ + e4 * 4);   \
            s0 += h4.x*w0.x + h4.y*w0.y + h4.z*w0.z + h4.w*w0.w;               \
            s1 += h4.x*w1.x + h4.y*w1.y + h4.z*w1.z + h4.w*w1.w;               \
        }                                                                      \
        __syncthreads();                                                       \
        for (int e4 = 38 + qg; e4 < 75; e4 += 8)                               \
            *(float4*)&eLT[e4 - 38][b31][0] = *(const float4*)(erow + e4 * 4); \
        __syncthreads();                                                       \
        _Pragma("unroll 2")                                                    \
        for (int e4 = 38; e4 < 75; ++e4) {                                     \
            float4 h4 = *(const float4*)&eLT[e4 - 38][b31][0];                 \
            float4 w0 = *(const float4*)(Wih + (size_t)grow0 * E_ + e4 * 4);   \
            float4 w1 = *(const float4*)(Wih + (size_t)grow1 * E_ + e4 * 4);   \
            s0 += h4.x*w0.x + h4.y*w0.y + h4.z*w0.z + h4.w*w0.w;               \
            s1 += h4.x*w1.x + h4.y*w1.y + h4.z*w1.z + h4.w*w1.w;               \
        }                                                                      \
        xg0 = s0; xg1 = s1;                                                    \
    }

    COMPUTE_XG(0);

    float c_reg = 0.f;                   // c owned exclusively by this WG
    const int bb = tid & 31;
    const int ul = (tid >> 5) & 3;

    for (int t = 0; t < T_; ++t) {
        // [A] stage h(t-1) (transposed layout; step 0 uses h = 0 -> skip dot)
        if (t > 0) {
            const float* hp = hbuf + (size_t)(dir * 2 + ((t - 1) & 1)) * (64 * 32 * 4);
            for (int e4 = qg; e4 < 64; e4 += 8)
                *(float4*)&hLT[e4][b31][0] = *(const float4*)(hp + (e4 * 32 + b31) * 4);
        }
        __syncthreads();

        // [B] gates = xg + Whh . h(t-1)
        float a0 = xg0, a1 = xg1;
        if (t > 0) {
#pragma unroll 4
            for (int e4 = 0; e4 < 64; ++e4) {
                float4 h4 = *(const float4*)&hLT[e4][b31][0];
                float4 w0 = *(const float4*)(Whh + (size_t)grow0 * H_ + e4 * 4);
                float4 w1 = *(const float4*)(Whh + (size_t)grow1 * H_ + e4 * 4);
                a0 += h4.x*w0.x + h4.y*w0.y + h4.z*w0.z + h4.w*w0.w;
                a1 += h4.x*w1.x + h4.y*w1.y + h4.z*w1.z + h4.w*w1.w;
            }
        }
        gbuf[lr0][b31] = a0;
        gbuf[lr1][b31] = a1;
        __syncthreads();

        // [D] nonlinearity + c/h update + fused output scatter (tid<128)
        if (tid < 128) {
            const int u = u0 + ul;
            float hnew;
            if (t < sL[bb]) {
                float gi = gbuf[ul][bb];
                float gf = gbuf[4 + ul][bb];
                float gg = gbuf[8 + ul][bb];
                float go = gbuf[12 + ul][bb];
                float si = 1.f / (1.f + expf(-gi));
                float sf = 1.f / (1.f + expf(-gf));
                float so = 1.f / (1.f + expf(-go));
                c_reg = sf * c_reg + si * tanhf(gg);
                hnew = so * tanhf(c_reg);
                if (dir == 0) {
                    int j = fslot[bb * T_ + t];
                    if (j >= 0) out[((size_t)bb * OUT_ + j) * 512 + u] = hnew;
                } else {
                    int p = bpos[bb * T_ + t];
                    if (p >= 0) out[((size_t)bb * OUT_ + p) * 512 + 256 + u] = hnew;
                }
            } else {
                hnew = hLT[u >> 2][bb][u & 3];   // frozen (t >= L >= 256 > 0)
            }
            float* hn = hbuf + (size_t)(dir * 2 + (t & 1)) * (64 * 32 * 4);
            hn[((u >> 2) * 32 + bb) * 4 + (u & 3)] = hnew;
        }
        __syncthreads();   // drains h stores (vmcnt) before the release below

        if (t + 1 < T_) {
            // [E] arrive: release publishes this WG's h(t) device-wide
            if (tid == 0) {
                int prev = __hip_atomic_fetch_add(cntp, 1, __ATOMIC_ACQ_REL,
                                                  __HIP_MEMORY_SCOPE_AGENT);
                if (prev == (t + 1) * NWG_ - 1)
                    __hip_atomic_store(genp, t + 1, __ATOMIC_RELEASE,
                                       __HIP_MEMORY_SCOPE_AGENT);
            }
            // [F] xg(t+1) — hides the barrier wait under useful work
            COMPUTE_XG(t + 1);
            // [G] relaxed poll (no per-poll cache inv), one acquire at exit
            if (tid == 0) {
                while (__hip_atomic_load(genp, __ATOMIC_RELAXED,
                                         __HIP_MEMORY_SCOPE_AGENT) < t + 1)
                    __builtin_amdgcn_s_sleep(1);
                (void)__hip_atomic_load(genp, __ATOMIC_ACQUIRE,
                                        __HIP_MEMORY_SCOPE_AGENT);
            }
            __syncthreads();
        }
    }
#undef COMPUTE_XG
}

// ---------------------------------------------------------------------------
extern "C" void kernel_launch(void* const* d_in, const int* in_sizes, int n_in,
                              void* d_out, int out_size, void* d_ws, size_t ws_size,
                              hipStream_t stream) {
    const int*           inputs = (const int*)d_in[0];
    const int*           seqlen = (const int*)d_in[1];
    const unsigned char* fm     = (const unsigned char*)d_in[2];
    const unsigned char* bm     = (const unsigned char*)d_in[3];
    // d_in[4] = out_seq_length (== 256, hardcoded)
    const float* emb  = (const float*)d_in[5];
    const float* Wihf = (const float*)d_in[6];
    const float* Whhf = (const float*)d_in[7];
    const float* bihf = (const float*)d_in[8];
    const float* bhhf = (const float*)d_in[9];
    const float* Wihb = (const float*)d_in[10];
    const float* Whhb = (const float*)d_in[11];
    const float* bihb = (const float*)d_in[12];
    const float* bhhb = (const float*)d_in[13];
    float* out = (float*)d_out;

    char* ws = (char*)d_ws;
    // ws layout (bytes):
    //   [0)       fslot int32[32][512]                      65536
    //   [65536)   bpos  int32[32][512]                      65536
    //   [131072)  h ping-pong f32[2 dir][2 par][64][32][4] 131072
    //   [262144)  barrier: cnt @ +0, gen @ +128              256
    int*   fslot = (int*)(ws);
    int*   bpos  = (int*)(ws + 65536);
    float* hbuf  = (float*)(ws + 131072);
    int*   cntp  = (int*)(ws + 262144);
    int*   genp  = (int*)(ws + 262144 + 128);
    (void)in_sizes; (void)n_in; (void)out_size; (void)ws_size;

    // reset barrier state every call (graph replays do not re-poison ws)
    hipMemsetAsync(ws + 262144, 0, 256, stream);
    slots_kernel<<<1, 64, 0, stream>>>(fm, bm, fslot, bpos);
    persist_lstm<<<NWG_, 256, 0, stream>>>(
        inputs, seqlen, emb,
        Wihf, Whhf, bihf, bhhf,
        Wihb, Whhb, bihb, bhhb,
        fslot, bpos, hbuf, cntp, genp, out);
}

// Round 4
// 7342.162 us; speedup vs baseline: 1.3588x; 1.3588x over previous
//
#include <hip/hip_runtime.h>
#include <hip/hip_bf16.h>

#define B_   32
#define T_   512
#define E_   300
#define H_   256
#define OUT_ 256
#define EPAD 304

// ---------------------------------------------------------------------------
// Slot tables: fslot[b][t] = index among True fmask positions (else -1)
//              bpos [b][t] = OUT-1-index among True bmask positions (else -1)
// Runtime-detects bool-byte vs int32 masks (exactly 256 True per row).
// ---------------------------------------------------------------------------
__global__ __launch_bounds__(64) void slots_kernel(
    const unsigned char* __restrict__ fm, const unsigned char* __restrict__ bm,
    int* __restrict__ fslot, int* __restrict__ bpos)
{
    int b = threadIdx.x;
    if (b >= B_) return;
    int cnt = 0;
    for (int t = 0; t < T_; ++t) cnt += (fm[b * T_ + t] != 0);
    bool isbool = (cnt == 256);
    const int* fmi = (const int*)fm;
    const int* bmi = (const int*)bm;
    int jf = 0, jb = 0;
    for (int t = 0; t < T_; ++t) {
        bool f = isbool ? (fm[b * T_ + t] != 0) : (fmi[b * T_ + t] != 0);
        bool g = isbool ? (bm[b * T_ + t] != 0) : (bmi[b * T_ + t] != 0);
        fslot[b * T_ + t] = f ? (jf++) : -1;
        bpos [b * T_ + t] = g ? (OUT_ - 1 - (jb++)) : -1;
    }
}

// ---------------------------------------------------------------------------
// xg GEMM (round-2 structure, known good): xg[(dir*Tc+tc)*1024*32 + row*32 + b]
//   = dot(emb[token(dir,b,t0+tc)], W_ih[row]) + b_ih[row] + b_hh[row]
// grid (16 row-blocks of 64, Tc, 2 dirs), block 256
// ---------------------------------------------------------------------------
__global__ __launch_bounds__(256) void xg_gemm(
    const int* __restrict__ inputs, const int* __restrict__ seqlen,
    const float* __restrict__ emb,
    const float* __restrict__ Wihf, const float* __restrict__ Wihb,
    const float* __restrict__ bihf, const float* __restrict__ bhhf,
    const float* __restrict__ bihb, const float* __restrict__ bhhb,
    float* __restrict__ xg, int t0, int TcMax)
{
    const int tc  = blockIdx.y;
    const int t   = t0 + tc;
    const int dir = blockIdx.z;
    const int rblk = blockIdx.x * 64;

    __shared__ float eL[B_][EPAD];

    for (int idx = threadIdx.x; idx < B_ * 75; idx += 256) {
        int b = idx / 75, q = idx - b * 75;
        int L = seqlen[b];
        int tt = t;
        if (dir) tt = (t < L) ? (L - 1 - t) : t;
        int tok = inputs[b * T_ + tt];
        float4 v = *(const float4*)(emb + (size_t)tok * E_ + q * 4);
        *(float4*)(&eL[b][q * 4]) = v;
    }
    __syncthreads();

    const float* W  = dir ? Wihb : Wihf;
    const float* bi = dir ? bihb : bihf;
    const float* bh = dir ? bhhb : bhhf;

    const int b  = threadIdx.x & 31;
    const int r8 = threadIdx.x >> 5;
    float acc[8];
#pragma unroll
    for (int m = 0; m < 8; ++m) acc[m] = 0.f;

    for (int e = 0; e < E_; e += 4) {
        float4 h4 = *(const float4*)(&eL[b][e]);
#pragma unroll
        for (int m = 0; m < 8; ++m) {
            int row = rblk + r8 + m * 8;
            float4 w4 = *(const float4*)(W + (size_t)row * E_ + e);
            acc[m] += h4.x * w4.x + h4.y * w4.y + h4.z * w4.z + h4.w * w4.w;
        }
    }

    float* outp = xg + (size_t)(dir * TcMax + tc) * (1024 * B_);
#pragma unroll
    for (int m = 0; m < 8; ++m) {
        int row = rblk + r8 + m * 8;
        outp[(size_t)row * B_ + b] = acc[m] + bi[row] + bh[row];
    }
}

// ---------------------------------------------------------------------------
// Persistent recurrence, W_hh in LDS. 256 WGs x 256 thr:
//   wg>>7 = dir, wgd = wg&127 -> 2 hidden units (8 gate rows).
// Thread (rp=tid>>5, b=tid&31) computes gate row rp (= gate*2+ul) for batch b.
// Per-dir device barrier (128 arrivals); xg prefetched 1 step ahead.
// c in regs (tid<64); c/h checkpointed in ws only at chunk boundaries.
// ---------------------------------------------------------------------------
__global__ __launch_bounds__(256) void persist_rec(
    const float* __restrict__ xg, const int* __restrict__ seqlen,
    const float* __restrict__ Whh_f, const float* __restrict__ Whh_b,
    const int* __restrict__ fslot, const int* __restrict__ bpos,
    float* __restrict__ hbuf, float* __restrict__ cbuf,
    int* __restrict__ barr, float* __restrict__ out, int t0, int Tc)
{
    const int wg   = blockIdx.x;
    const int dir  = wg >> 7;
    const int wgd  = wg & 127;
    const int u0   = wgd * 2;
    const int tid  = threadIdx.x;
    const int b31  = tid & 31;
    const int rp   = tid >> 5;            // 0..7 = gate*2 + ul
    const int grow = (rp >> 1) * H_ + u0 + (rp & 1);

    __shared__ float WhhL[8][256];        // 8 KB, staged once
    __shared__ float hLT[64][32][4];      // 32 KB, h(t-1) transposed [k4][b]
    __shared__ float gbuf[8][33];
    __shared__ int   sL[B_];

    const float* Whh = dir ? Whh_b : Whh_f;
#pragma unroll
    for (int i = 0; i < 2; ++i) {
        int k4 = b31 + 32 * i;
        *(float4*)&WhhL[rp][k4 * 4] = *(const float4*)(Whh + (size_t)grow * H_ + k4 * 4);
    }
    if (tid < B_) sL[tid] = seqlen[tid];
    __syncthreads();

    int* cntp = barr + dir * 64;          // 256 B apart per dir
    int* genp = barr + dir * 64 + 32;     // 128 B from cnt: separate line

    const int ul2 = (tid >> 5) & 1, bb = tid & 31;   // for tid<64 epilogue
    float c_reg = 0.f;
    if (t0 > 0 && tid < 64)
        c_reg = cbuf[((size_t)(dir * 128 + wgd) * 2 + ul2) * 32 + bb];

    float xg_cur = xg[(size_t)(dir * Tc) * 32768 + (size_t)grow * 32 + b31];

    for (int tc = 0; tc < Tc; ++tc) {
        const int t = t0 + tc;

        // prefetch next step's xg before the poll (independent, hides latency)
        float xg_next = 0.f;
        if (tc + 1 < Tc)
            xg_next = xg[(size_t)(dir * Tc + tc + 1) * 32768 + (size_t)grow * 32 + b31];

        if (tc > 0) {
            if (tid == 0) {
                while (__hip_atomic_load(genp, __ATOMIC_RELAXED,
                                         __HIP_MEMORY_SCOPE_AGENT) < tc)
                    __builtin_amdgcn_s_sleep(1);
                (void)__hip_atomic_load(genp, __ATOMIC_ACQUIRE,
                                        __HIP_MEMORY_SCOPE_AGENT);
            }
            __syncthreads();
        }
        if (t > 0) {   // stage h(t-1): 32 KB, coalesced, transposed layout
            const float* hp = hbuf + (size_t)(dir * 2 + ((t - 1) & 1)) * (64 * 32 * 4);
#pragma unroll
            for (int i = 0; i < 8; ++i) {
                int f4 = tid + 256 * i;
                *(float4*)&hLT[f4 >> 5][f4 & 31][0] = *((const float4*)hp + f4);
            }
        }
        __syncthreads();

        float a = xg_cur;
        if (t > 0) {
#pragma unroll 8
            for (int k4 = 0; k4 < 64; ++k4) {
                float4 h4 = *(const float4*)&hLT[k4][b31][0];
                float4 w4 = *(const float4*)&WhhL[rp][k4 * 4];
                a += h4.x * w4.x + h4.y * w4.y + h4.z * w4.z + h4.w * w4.w;
            }
        }
        gbuf[rp][b31] = a;
        __syncthreads();

        if (tid < 64) {
            const int u = u0 + ul2;
            float hnew;
            if (t < sL[bb]) {
                float gi = gbuf[0 + ul2][bb];
                float gf = gbuf[2 + ul2][bb];
                float gg = gbuf[4 + ul2][bb];
                float go = gbuf[6 + ul2][bb];
                float si = 1.f / (1.f + expf(-gi));
                float sf = 1.f / (1.f + expf(-gf));
                float so = 1.f / (1.f + expf(-go));
                c_reg = sf * c_reg + si * tanhf(gg);
                hnew  = so * tanhf(c_reg);
                if (dir == 0) {
                    int j = fslot[bb * T_ + t];
                    if (j >= 0) out[((size_t)bb * OUT_ + j) * 512 + u] = hnew;
                } else {
                    int p = bpos[bb * T_ + t];
                    if (p >= 0) out[((size_t)bb * OUT_ + p) * 512 + 256 + u] = hnew;
                }
            } else {
                hnew = hLT[u >> 2][bb][u & 3];   // frozen (t >= L >= 256 > 0)
            }
            float* hn = hbuf + (size_t)(dir * 2 + (t & 1)) * (64 * 32 * 4);
            hn[((u >> 2) * 32 + bb) * 4 + (u & 3)] = hnew;
        }
        xg_cur = xg_next;
        __syncthreads();   // h stores (wave 0) drained via per-wave vmcnt at barrier

        if (tc + 1 < Tc) {
            if (tid == 0) {   // release publishes wave-0's h stores device-wide
                int prev = __hip_atomic_fetch_add(cntp, 1, __ATOMIC_ACQ_REL,
                                                  __HIP_MEMORY_SCOPE_AGENT);
                if (prev == (tc + 1) * 128 - 1)
                    __hip_atomic_store(genp, tc + 1, __ATOMIC_RELEASE,
                                       __HIP_MEMORY_SCOPE_AGENT);
            }
        }
    }

    if (tid < 64)   // checkpoint c for next chunk (chunk 0 re-inits to 0)
        cbuf[((size_t)(dir * 128 + wgd) * 2 + ul2) * 32 + bb] = c_reg;
}

// ---------------------------------------------------------------------------
extern "C" void kernel_launch(void* const* d_in, const int* in_sizes, int n_in,
                              void* d_out, int out_size, void* d_ws, size_t ws_size,
                              hipStream_t stream) {
    const int*           inputs = (const int*)d_in[0];
    const int*           seqlen = (const int*)d_in[1];
    const unsigned char* fm     = (const unsigned char*)d_in[2];
    const unsigned char* bm     = (const unsigned char*)d_in[3];
    // d_in[4] = out_seq_length (== 256, hardcoded)
    const float* emb  = (const float*)d_in[5];
    const float* Wihf = (const float*)d_in[6];
    const float* Whhf = (const float*)d_in[7];
    const float* bihf = (const float*)d_in[8];
    const float* bhhf = (const float*)d_in[9];
    const float* Wihb = (const float*)d_in[10];
    const float* Whhb = (const float*)d_in[11];
    const float* bihb = (const float*)d_in[12];
    const float* bhhb = (const float*)d_in[13];
    float* out = (float*)d_out;

    char* ws = (char*)d_ws;
    // ws layout (bytes):
    //   [0)       fslot int32[32][512]                      65536
    //   [65536)   bpos  int32[32][512]                      65536
    //   [131072)  h ping-pong f32[2dir][2par][64][32][4]   131072
    //   [262144)  c checkpoint f32[2dir][128][2][32]        65536
    //   [327680)  barriers: per dir {cnt@+0, gen@+128} x2     512
    //   [393216)  xg f32[2dir][Tc][1024][32]           Tc*262144
    int*   fslot = (int*)(ws);
    int*   bpos  = (int*)(ws + 65536);
    float* hbuf  = (float*)(ws + 131072);
    float* cbuf  = (float*)(ws + 262144);
    int*   barr  = (int*)(ws + 327680);
    float* xg    = (float*)(ws + 393216);
    (void)in_sizes; (void)n_in; (void)out_size;

    size_t avail = (ws_size > 393216) ? ws_size - 393216 : 0;
    int Tc = 1;
    for (int c = 512; c >= 1; c >>= 1)
        if ((size_t)c * 262144 <= avail) { Tc = c; break; }

    slots_kernel<<<1, 64, 0, stream>>>(fm, bm, fslot, bpos);

    for (int t0 = 0; t0 < T_; t0 += Tc) {
        dim3 g(16, Tc, 2);
        xg_gemm<<<g, 256, 0, stream>>>(inputs, seqlen, emb, Wihf, Wihb,
                                       bihf, bhhf, bihb, bhhb, xg, t0, Tc);
        hipMemsetAsync(barr, 0, 512, stream);   // reset barrier for this chunk
        persist_rec<<<256, 256, 0, stream>>>(xg, seqlen, Whhf, Whhb,
                                             fslot, bpos, hbuf, cbuf, barr, out, t0, Tc);
    }
}

// Round 5
// 5804.061 us; speedup vs baseline: 1.7189x; 1.2650x over previous
//
#include <hip/hip_runtime.h>
#include <hip/hip_bf16.h>

#define B_   32
#define T_   512
#define E_   300
#define H_   256
#define OUT_ 256
#define EPAD 304

// ---------------------------------------------------------------------------
// Slot tables (unchanged, known good).
// ---------------------------------------------------------------------------
__global__ __launch_bounds__(64) void slots_kernel(
    const unsigned char* __restrict__ fm, const unsigned char* __restrict__ bm,
    int* __restrict__ fslot, int* __restrict__ bpos)
{
    int b = threadIdx.x;
    if (b >= B_) return;
    int cnt = 0;
    for (int t = 0; t < T_; ++t) cnt += (fm[b * T_ + t] != 0);
    bool isbool = (cnt == 256);
    const int* fmi = (const int*)fm;
    const int* bmi = (const int*)bm;
    int jf = 0, jb = 0;
    for (int t = 0; t < T_; ++t) {
        bool f = isbool ? (fm[b * T_ + t] != 0) : (fmi[b * T_ + t] != 0);
        bool g = isbool ? (bm[b * T_ + t] != 0) : (bmi[b * T_ + t] != 0);
        fslot[b * T_ + t] = f ? (jf++) : -1;
        bpos [b * T_ + t] = g ? (OUT_ - 1 - (jb++)) : -1;
    }
}

// ---------------------------------------------------------------------------
// xg GEMM (unchanged, known good).
// ---------------------------------------------------------------------------
__global__ __launch_bounds__(256) void xg_gemm(
    const int* __restrict__ inputs, const int* __restrict__ seqlen,
    const float* __restrict__ emb,
    const float* __restrict__ Wihf, const float* __restrict__ Wihb,
    const float* __restrict__ bihf, const float* __restrict__ bhhf,
    const float* __restrict__ bihb, const float* __restrict__ bhhb,
    float* __restrict__ xg, int t0, int TcMax)
{
    const int tc  = blockIdx.y;
    const int t   = t0 + tc;
    const int dir = blockIdx.z;
    const int rblk = blockIdx.x * 64;

    __shared__ float eL[B_][EPAD];

    for (int idx = threadIdx.x; idx < B_ * 75; idx += 256) {
        int b = idx / 75, q = idx - b * 75;
        int L = seqlen[b];
        int tt = t;
        if (dir) tt = (t < L) ? (L - 1 - t) : t;
        int tok = inputs[b * T_ + tt];
        float4 v = *(const float4*)(emb + (size_t)tok * E_ + q * 4);
        *(float4*)(&eL[b][q * 4]) = v;
    }
    __syncthreads();

    const float* W  = dir ? Wihb : Wihf;
    const float* bi = dir ? bihb : bihf;
    const float* bh = dir ? bhhb : bhhf;

    const int b  = threadIdx.x & 31;
    const int r8 = threadIdx.x >> 5;
    float acc[8];
#pragma unroll
    for (int m = 0; m < 8; ++m) acc[m] = 0.f;

    for (int e = 0; e < E_; e += 4) {
        float4 h4 = *(const float4*)(&eL[b][e]);
#pragma unroll
        for (int m = 0; m < 8; ++m) {
            int row = rblk + r8 + m * 8;
            float4 w4 = *(const float4*)(W + (size_t)row * E_ + e);
            acc[m] += h4.x * w4.x + h4.y * w4.y + h4.z * w4.z + h4.w * w4.w;
        }
    }

    float* outp = xg + (size_t)(dir * TcMax + tc) * (1024 * B_);
#pragma unroll
    for (int m = 0; m < 8; ++m) {
        int row = rblk + r8 + m * 8;
        outp[(size_t)row * B_ + b] = acc[m] + bi[row] + bh[row];
    }
}

// ---------------------------------------------------------------------------
// Persistent recurrence v2: 128 WGs (64/dir) x 512 thr, 4 hidden units/WG.
// Flag-array barrier: arrive = 1 release store to own 128B slot; wait =
// wave0's 64 lanes poll the dir's 64 flags in parallel (relaxed) + __all,
// then __threadfence. No contended atomics.
// Thread (rq=gate, kh=k-quarter, b): 4 rows x 64 k partial dot; partials
// reduced via gbuf in epilogue. W_hh rows in LDS (16 KB). c in regs.
// ---------------------------------------------------------------------------
__global__ __launch_bounds__(512) void persist_rec(
    const float* __restrict__ xg, const int* __restrict__ seqlen,
    const float* __restrict__ Whh_f, const float* __restrict__ Whh_b,
    const int* __restrict__ fslot, const int* __restrict__ bpos,
    float* __restrict__ hbuf, float* __restrict__ cbuf,
    int* __restrict__ barr, float* __restrict__ out, int t0, int Tc)
{
    const int wg  = blockIdx.x;          // 0..127
    const int dir = wg >> 6;
    const int wgd = wg & 63;
    const int u0  = wgd * 4;
    const int tid = threadIdx.x;
    const int b31 = tid & 31;
    const int kh  = (tid >> 5) & 3;      // k-quarter
    const int rq  = tid >> 7;            // gate 0..3

    __shared__ float WhhL[16][256];      // 16 KB (rows lr = gate*4 + unit)
    __shared__ float hLT[64][32][4];     // 32 KB h(t-1) transposed [k4][b][j]
    __shared__ float gbuf[16][4][33];    // partial gates [lr][kh][b], 8.4 KB
    __shared__ int   sL[B_];

    // stage W_hh rows for this WG's 4 units (16 rows x 256 f = 1024 float4)
    const float* Whh = dir ? Whh_b : Whh_f;
#pragma unroll
    for (int i = 0; i < 2; ++i) {
        int idx = tid + 512 * i;         // 0..1023
        int lr = idx >> 6, k4 = idx & 63;
        int grow = (lr >> 2) * H_ + u0 + (lr & 3);
        *(float4*)&WhhL[lr][k4 * 4] = *(const float4*)(Whh + (size_t)grow * H_ + k4 * 4);
    }
    if (tid < B_) sL[tid] = seqlen[tid];
    __syncthreads();

    const int ul = (tid >> 5) & 3, bb = tid & 31;   // epilogue mapping (tid<128)
    float c_reg = 0.f;
    if (t0 > 0 && tid < 128)
        c_reg = cbuf[(size_t)(dir * 64 + wgd) * 128 + ul * 32 + bb];

    // current-step xg (4 gates) for epilogue threads
    float xgv0 = 0.f, xgv1 = 0.f, xgv2 = 0.f, xgv3 = 0.f;
    if (tid < 128) {
        const float* xp = xg + (size_t)(dir * Tc) * 32768 + (u0 + ul) * 32 + bb;
        xgv0 = xp[0];
        xgv1 = xp[256 * 32];
        xgv2 = xp[512 * 32];
        xgv3 = xp[768 * 32];
    }

    int* myflag = barr + (size_t)wg * 32;            // 128B-spaced own slot

    for (int tc = 0; tc < Tc; ++tc) {
        const int t = t0 + tc;

        // prefetch next step's xg before the wait (independent loads)
        float xgn0 = 0.f, xgn1 = 0.f, xgn2 = 0.f, xgn3 = 0.f;
        if (tc + 1 < Tc && tid < 128) {
            const float* xp = xg + (size_t)(dir * Tc + tc + 1) * 32768 + (u0 + ul) * 32 + bb;
            xgn0 = xp[0];
            xgn1 = xp[256 * 32];
            xgn2 = xp[512 * 32];
            xgn3 = xp[768 * 32];
        }

        if (tc > 0) {
            if (tid < 64) {   // parallel poll: lane <-> flag of this dir
                const int* fp = barr + (size_t)(dir * 64 + tid) * 32;
                while (!__all(__hip_atomic_load(fp, __ATOMIC_RELAXED,
                                                __HIP_MEMORY_SCOPE_AGENT) >= tc))
                    __builtin_amdgcn_s_sleep(1);
                __threadfence();   // acquire: order h reads after observed releases
            }
            __syncthreads();
        }

        // stage h(t-1): 32 KB coalesced (2048 float4 / 512 thr = 4 each)
        if (t > 0) {
            const float* hp = hbuf + (size_t)(dir * 2 + ((t - 1) & 1)) * (64 * 32 * 4);
#pragma unroll
            for (int i = 0; i < 4; ++i) {
                int f4 = tid + 512 * i;
                *(float4*)&hLT[f4 >> 5][f4 & 31][0] = *((const float4*)hp + f4);
            }
        }
        __syncthreads();

        // partial dot: gate rq, units u0..u0+3, k in [kh*64, kh*64+64)
        float a0 = 0.f, a1 = 0.f, a2 = 0.f, a3 = 0.f;
        if (t > 0) {
#pragma unroll 4
            for (int kk = 0; kk < 16; ++kk) {
                int k4 = kh * 16 + kk;
                float4 h4 = *(const float4*)&hLT[k4][b31][0];
                float4 w0 = *(const float4*)&WhhL[rq * 4 + 0][k4 * 4];
                float4 w1 = *(const float4*)&WhhL[rq * 4 + 1][k4 * 4];
                float4 w2 = *(const float4*)&WhhL[rq * 4 + 2][k4 * 4];
                float4 w3 = *(const float4*)&WhhL[rq * 4 + 3][k4 * 4];
                a0 += h4.x*w0.x + h4.y*w0.y + h4.z*w0.z + h4.w*w0.w;
                a1 += h4.x*w1.x + h4.y*w1.y + h4.z*w1.z + h4.w*w1.w;
                a2 += h4.x*w2.x + h4.y*w2.y + h4.z*w2.z + h4.w*w2.w;
                a3 += h4.x*w3.x + h4.y*w3.y + h4.z*w3.z + h4.w*w3.w;
            }
        }
        gbuf[rq * 4 + 0][kh][b31] = a0;
        gbuf[rq * 4 + 1][kh][b31] = a1;
        gbuf[rq * 4 + 2][kh][b31] = a2;
        gbuf[rq * 4 + 3][kh][b31] = a3;
        __syncthreads();

        // epilogue: thread (ul, bb) handles unit u0+ul, batch bb
        if (tid < 128) {
            const int u = u0 + ul;
            float hnew;
            if (t < sL[bb]) {
                float gi = xgv0, gf = xgv1, gg = xgv2, go = xgv3;
                if (t > 0) {
#pragma unroll
                    for (int q = 0; q < 4; ++q) {
                        gi += gbuf[0  + ul][q][bb];
                        gf += gbuf[4  + ul][q][bb];
                        gg += gbuf[8  + ul][q][bb];
                        go += gbuf[12 + ul][q][bb];
                    }
                }
                float si = 1.f / (1.f + expf(-gi));
                float sf = 1.f / (1.f + expf(-gf));
                float so = 1.f / (1.f + expf(-go));
                c_reg = sf * c_reg + si * tanhf(gg);
                hnew  = so * tanhf(c_reg);
                if (dir == 0) {
                    int j = fslot[bb * T_ + t];
                    if (j >= 0) out[((size_t)bb * OUT_ + j) * 512 + u] = hnew;
                } else {
                    int p = bpos[bb * T_ + t];
                    if (p >= 0) out[((size_t)bb * OUT_ + p) * 512 + 256 + u] = hnew;
                }
            } else {
                hnew = hLT[wgd][bb][ul];   // frozen (t >= L >= 256 > 0)
            }
            // h line [k4=wgd][b][j]: 512B owned exclusively by this WG
            float* hn = hbuf + (size_t)(dir * 2 + (t & 1)) * (64 * 32 * 4);
            hn[(wgd * 32 + bb) * 4 + ul] = hnew;
        }
        xgv0 = xgn0; xgv1 = xgn1; xgv2 = xgn2; xgv3 = xgn3;
        __syncthreads();   // drain h stores (per-wave vmcnt) before release

        if (tc + 1 < Tc && tid == 0)
            __hip_atomic_store(myflag, tc + 1, __ATOMIC_RELEASE,
                               __HIP_MEMORY_SCOPE_AGENT);
    }

    if (tid < 128)   // checkpoint c for next chunk
        cbuf[(size_t)(dir * 64 + wgd) * 128 + ul * 32 + bb] = c_reg;
}

// ---------------------------------------------------------------------------
extern "C" void kernel_launch(void* const* d_in, const int* in_sizes, int n_in,
                              void* d_out, int out_size, void* d_ws, size_t ws_size,
                              hipStream_t stream) {
    const int*           inputs = (const int*)d_in[0];
    const int*           seqlen = (const int*)d_in[1];
    const unsigned char* fm     = (const unsigned char*)d_in[2];
    const unsigned char* bm     = (const unsigned char*)d_in[3];
    // d_in[4] = out_seq_length (== 256, hardcoded)
    const float* emb  = (const float*)d_in[5];
    const float* Wihf = (const float*)d_in[6];
    const float* Whhf = (const float*)d_in[7];
    const float* bihf = (const float*)d_in[8];
    const float* bhhf = (const float*)d_in[9];
    const float* Wihb = (const float*)d_in[10];
    const float* Whhb = (const float*)d_in[11];
    const float* bihb = (const float*)d_in[12];
    const float* bhhb = (const float*)d_in[13];
    float* out = (float*)d_out;

    char* ws = (char*)d_ws;
    // ws layout (bytes):
    //   [0)       fslot int32[32][512]                      65536
    //   [65536)   bpos  int32[32][512]                      65536
    //   [131072)  h ping-pong f32[2dir][2par][64][32][4]   131072
    //   [262144)  c checkpoint f32[2dir][64][4][32]         65536
    //   [327680)  flags: 128 slots x 128 B                  16384
    //   [393216)  xg f32[2dir][Tc][1024][32]           Tc*262144
    int*   fslot = (int*)(ws);
    int*   bpos  = (int*)(ws + 65536);
    float* hbuf  = (float*)(ws + 131072);
    float* cbuf  = (float*)(ws + 262144);
    int*   barr  = (int*)(ws + 327680);
    float* xg    = (float*)(ws + 393216);
    (void)in_sizes; (void)n_in; (void)out_size;

    size_t avail = (ws_size > 393216) ? ws_size - 393216 : 0;
    int Tc = 1;
    for (int c = 512; c >= 1; c >>= 1)
        if ((size_t)c * 262144 <= avail) { Tc = c; break; }

    slots_kernel<<<1, 64, 0, stream>>>(fm, bm, fslot, bpos);

    for (int t0 = 0; t0 < T_; t0 += Tc) {
        dim3 g(16, Tc, 2);
        xg_gemm<<<g, 256, 0, stream>>>(inputs, seqlen, emb, Wihf, Wihb,
                                       bihf, bhhf, bihb, bhhb, xg, t0, Tc);
        hipMemsetAsync(barr, 0, 16384, stream);   // reset flags for this chunk
        persist_rec<<<128, 512, 0, stream>>>(xg, seqlen, Whhf, Whhb,
                                             fslot, bpos, hbuf, cbuf, barr, out, t0, Tc);
    }
}

// Round 6
// 5495.815 us; speedup vs baseline: 1.8153x; 1.0561x over previous
//
#include <hip/hip_runtime.h>
#include <hip/hip_bf16.h>

#define B_   32
#define T_   512
#define E_   300
#define H_   256
#define OUT_ 256
#define EPAD 304
#define GROWP 293   // gbuf row stride (32*9 + 5): breaks 32-word alignment

// ---------------------------------------------------------------------------
// Slot tables (unchanged, known good).
// ---------------------------------------------------------------------------
__global__ __launch_bounds__(64) void slots_kernel(
    const unsigned char* __restrict__ fm, const unsigned char* __restrict__ bm,
    int* __restrict__ fslot, int* __restrict__ bpos)
{
    int b = threadIdx.x;
    if (b >= B_) return;
    int cnt = 0;
    for (int t = 0; t < T_; ++t) cnt += (fm[b * T_ + t] != 0);
    bool isbool = (cnt == 256);
    const int* fmi = (const int*)fm;
    const int* bmi = (const int*)bm;
    int jf = 0, jb = 0;
    for (int t = 0; t < T_; ++t) {
        bool f = isbool ? (fm[b * T_ + t] != 0) : (fmi[b * T_ + t] != 0);
        bool g = isbool ? (bm[b * T_ + t] != 0) : (bmi[b * T_ + t] != 0);
        fslot[b * T_ + t] = f ? (jf++) : -1;
        bpos [b * T_ + t] = g ? (OUT_ - 1 - (jb++)) : -1;
    }
}

// ---------------------------------------------------------------------------
// xg GEMM (unchanged, known good).
// ---------------------------------------------------------------------------
__global__ __launch_bounds__(256) void xg_gemm(
    const int* __restrict__ inputs, const int* __restrict__ seqlen,
    const float* __restrict__ emb,
    const float* __restrict__ Wihf, const float* __restrict__ Wihb,
    const float* __restrict__ bihf, const float* __restrict__ bhhf,
    const float* __restrict__ bihb, const float* __restrict__ bhhb,
    float* __restrict__ xg, int t0, int TcMax)
{
    const int tc  = blockIdx.y;
    const int t   = t0 + tc;
    const int dir = blockIdx.z;
    const int rblk = blockIdx.x * 64;

    __shared__ float eL[B_][EPAD];

    for (int idx = threadIdx.x; idx < B_ * 75; idx += 256) {
        int b = idx / 75, q = idx - b * 75;
        int L = seqlen[b];
        int tt = t;
        if (dir) tt = (t < L) ? (L - 1 - t) : t;
        int tok = inputs[b * T_ + tt];
        float4 v = *(const float4*)(emb + (size_t)tok * E_ + q * 4);
        *(float4*)(&eL[b][q * 4]) = v;
    }
    __syncthreads();

    const float* W  = dir ? Wihb : Wihf;
    const float* bi = dir ? bihb : bihf;
    const float* bh = dir ? bhhb : bhhf;

    const int b  = threadIdx.x & 31;
    const int r8 = threadIdx.x >> 5;
    float acc[8];
#pragma unroll
    for (int m = 0; m < 8; ++m) acc[m] = 0.f;

    for (int e = 0; e < E_; e += 4) {
        float4 h4 = *(const float4*)(&eL[b][e]);
#pragma unroll
        for (int m = 0; m < 8; ++m) {
            int row = rblk + r8 + m * 8;
            float4 w4 = *(const float4*)(W + (size_t)row * E_ + e);
            acc[m] += h4.x * w4.x + h4.y * w4.y + h4.z * w4.z + h4.w * w4.w;
        }
    }

    float* outp = xg + (size_t)(dir * TcMax + tc) * (1024 * B_);
#pragma unroll
    for (int m = 0; m < 8; ++m) {
        int row = rblk + r8 + m * 8;
        outp[(size_t)row * B_ + b] = acc[m] + bi[row] + bh[row];
    }
}

// ---------------------------------------------------------------------------
// Persistent recurrence v3: 128 WGs (64/dir) x 512 thr, 4 units/WG.
// W_hh slice PERMANENTLY IN VGPRS (w[4][16] per thread; never re-read).
// Dot tiling: thread (rg=gate, bgr=b-quad, kq=k16-group) computes
// 4 rows x 4 batches x 16 k = 256 MAC; only LDS input is h, read as 16
// conflict-free ds_read_b128 from a block-permuted layout hP:
//   block(kq,bgr) (68-word padded) holds h[k=16kq..+16][b=4bgr..+4], k-major.
// kq-pair partials reduced via shfl_xor(32) (same wave), then gbuf.
// Flag-array barrier unchanged (round-5, proven).
// ---------------------------------------------------------------------------
__global__ __launch_bounds__(512, 2) void persist_rec(
    const float* __restrict__ xg, const int* __restrict__ seqlen,
    const float* __restrict__ Whh_f, const float* __restrict__ Whh_b,
    const int* __restrict__ fslot, const int* __restrict__ bpos,
    float* __restrict__ hbuf, float* __restrict__ cbuf,
    int* __restrict__ barr, float* __restrict__ out, int t0, int Tc)
{
    const int wg  = blockIdx.x;          // 0..127
    const int dir = wg >> 6;
    const int wgd = wg & 63;
    const int u0  = wgd * 4;
    const int tid = threadIdx.x;

    // dot-phase mapping
    const int rg  = tid & 3;             // gate 0..3
    const int bgr = (tid >> 2) & 7;      // batch-quad 0..7
    const int kq  = tid >> 5;            // k16-group 0..15

    __shared__ float hP[128 * 68];       // permuted h(t-1), 34.8 KB
    __shared__ float gbuf[16 * GROWP];   // partials [lr][b][kq2], 18.8 KB
    __shared__ int   sL[B_];

    // W_hh slice -> registers, once (rows = gate rg, units u0..u0+3; k-slice kq)
    const float* Whh = dir ? Whh_b : Whh_f;
    float w[4][16];
#pragma unroll
    for (int r = 0; r < 4; ++r) {
        const float* wr = Whh + (size_t)(rg * H_ + u0 + r) * H_ + kq * 16;
#pragma unroll
        for (int q = 0; q < 4; ++q) {
            float4 v = *(const float4*)(wr + q * 4);
            w[r][q * 4 + 0] = v.x; w[r][q * 4 + 1] = v.y;
            w[r][q * 4 + 2] = v.z; w[r][q * 4 + 3] = v.w;
        }
    }
    if (tid < B_) sL[tid] = seqlen[tid];
    __syncthreads();

    const int ul = (tid >> 5) & 3, bb = tid & 31;   // epilogue mapping (tid<128)
    float c_reg = 0.f;
    if (t0 > 0 && tid < 128)
        c_reg = cbuf[(size_t)(dir * 64 + wgd) * 128 + ul * 32 + bb];

    // current-step xg (4 gates) for epilogue threads
    float xgv0 = 0.f, xgv1 = 0.f, xgv2 = 0.f, xgv3 = 0.f;
    if (tid < 128) {
        const float* xp = xg + (size_t)(dir * Tc) * 32768 + (u0 + ul) * 32 + bb;
        xgv0 = xp[0];
        xgv1 = xp[256 * 32];
        xgv2 = xp[512 * 32];
        xgv3 = xp[768 * 32];
    }

    int* myflag = barr + (size_t)wg * 32;            // 128B-spaced own slot

    for (int tc = 0; tc < Tc; ++tc) {
        const int t = t0 + tc;

        // prefetch next step's xg before the wait (independent loads)
        float xgn0 = 0.f, xgn1 = 0.f, xgn2 = 0.f, xgn3 = 0.f;
        if (tc + 1 < Tc && tid < 128) {
            const float* xp = xg + (size_t)(dir * Tc + tc + 1) * 32768 + (u0 + ul) * 32 + bb;
            xgn0 = xp[0];
            xgn1 = xp[256 * 32];
            xgn2 = xp[512 * 32];
            xgn3 = xp[768 * 32];
        }

        if (tc > 0) {
            if (tid < 64) {   // parallel poll: lane <-> flag of this dir
                const int* fp = barr + (size_t)(dir * 64 + tid) * 32;
                while (!__all(__hip_atomic_load(fp, __ATOMIC_RELAXED,
                                                __HIP_MEMORY_SCOPE_AGENT) >= tc))
                    __builtin_amdgcn_s_sleep(1);
                __threadfence();   // acquire: order h reads after observed releases
            }
            __syncthreads();
        }

        // stage h(t-1) into permuted hP (global layout [k4][b][j] unchanged)
        if (t > 0) {
            const float* hp = hbuf + (size_t)(dir * 2 + ((t - 1) & 1)) * (64 * 32 * 4);
#pragma unroll
            for (int i = 0; i < 4; ++i) {
                int f4 = tid + 512 * i;          // 0..2047
                int k4 = f4 >> 5, b = f4 & 31;
                float4 v = *((const float4*)hp + f4);
                int base = ((k4 >> 2) * 8 + (b >> 2)) * 68 + (k4 & 3) * 16 + (b & 3);
                hP[base + 0]  = v.x;   // k = 4*k4 + j  ->  word off (k&15)*4 + (b&3)
                hP[base + 4]  = v.y;
                hP[base + 8]  = v.z;
                hP[base + 12] = v.w;
            }
        }
        __syncthreads();

        // dot: acc[r][bi] over this thread's 16 k's (W from registers)
        float acc[4][4];
#pragma unroll
        for (int r = 0; r < 4; ++r)
#pragma unroll
            for (int bi = 0; bi < 4; ++bi) acc[r][bi] = 0.f;

        if (t > 0) {
            const float* hblk = &hP[(kq * 8 + bgr) * 68];
#pragma unroll
            for (int kk = 0; kk < 16; ++kk) {
                float4 h4 = *(const float4*)(hblk + kk * 4);
#pragma unroll
                for (int r = 0; r < 4; ++r) {
                    acc[r][0] += w[r][kk] * h4.x;
                    acc[r][1] += w[r][kk] * h4.y;
                    acc[r][2] += w[r][kk] * h4.z;
                    acc[r][3] += w[r][kk] * h4.w;
                }
            }
        }

        // fold kq-pairs (lanes 32 apart, same wave), halves gbuf traffic
#pragma unroll
        for (int r = 0; r < 4; ++r)
#pragma unroll
            for (int bi = 0; bi < 4; ++bi)
                acc[r][bi] += __shfl_xor(acc[r][bi], 32, 64);

        if (((tid >> 5) & 1) == 0) {
            const int kq2 = kq >> 1;             // 0..7, one per wave
#pragma unroll
            for (int r = 0; r < 4; ++r)
#pragma unroll
                for (int bi = 0; bi < 4; ++bi)
                    gbuf[(rg * 4 + r) * GROWP + (bgr * 4 + bi) * 9 + kq2] = acc[r][bi];
        }
        __syncthreads();

        // epilogue: thread (ul, bb) handles unit u0+ul, batch bb
        if (tid < 128) {
            const int u = u0 + ul;
            float hnew;
            if (t < sL[bb]) {
                float gi = xgv0, gf = xgv1, gg = xgv2, go = xgv3;
#pragma unroll
                for (int q = 0; q < 8; ++q) {
                    gi += gbuf[(0  + ul) * GROWP + bb * 9 + q];
                    gf += gbuf[(4  + ul) * GROWP + bb * 9 + q];
                    gg += gbuf[(8  + ul) * GROWP + bb * 9 + q];
                    go += gbuf[(12 + ul) * GROWP + bb * 9 + q];
                }
                float si = 1.f / (1.f + expf(-gi));
                float sf = 1.f / (1.f + expf(-gf));
                float so = 1.f / (1.f + expf(-go));
                c_reg = sf * c_reg + si * tanhf(gg);
                hnew  = so * tanhf(c_reg);
                if (dir == 0) {
                    int j = fslot[bb * T_ + t];
                    if (j >= 0) out[((size_t)bb * OUT_ + j) * 512 + u] = hnew;
                } else {
                    int p = bpos[bb * T_ + t];
                    if (p >= 0) out[((size_t)bb * OUT_ + p) * 512 + 256 + u] = hnew;
                }
            } else {
                // frozen (t >= L >= 256 > 0): read h_old[u][bb] from hP
                hnew = hP[((u >> 4) * 8 + (bb >> 2)) * 68 + (u & 15) * 4 + (bb & 3)];
            }
            float* hn = hbuf + (size_t)(dir * 2 + (t & 1)) * (64 * 32 * 4);
            hn[(wgd * 32 + bb) * 4 + ul] = hnew;
        }
        xgv0 = xgn0; xgv1 = xgn1; xgv2 = xgn2; xgv3 = xgn3;
        __syncthreads();   // drain h stores before release

        if (tc + 1 < Tc && tid == 0)
            __hip_atomic_store(myflag, tc + 1, __ATOMIC_RELEASE,
                               __HIP_MEMORY_SCOPE_AGENT);
    }

    if (tid < 128)   // checkpoint c for next chunk
        cbuf[(size_t)(dir * 64 + wgd) * 128 + ul * 32 + bb] = c_reg;
}

// ---------------------------------------------------------------------------
extern "C" void kernel_launch(void* const* d_in, const int* in_sizes, int n_in,
                              void* d_out, int out_size, void* d_ws, size_t ws_size,
                              hipStream_t stream) {
    const int*           inputs = (const int*)d_in[0];
    const int*           seqlen = (const int*)d_in[1];
    const unsigned char* fm     = (const unsigned char*)d_in[2];
    const unsigned char* bm     = (const unsigned char*)d_in[3];
    // d_in[4] = out_seq_length (== 256, hardcoded)
    const float* emb  = (const float*)d_in[5];
    const float* Wihf = (const float*)d_in[6];
    const float* Whhf = (const float*)d_in[7];
    const float* bihf = (const float*)d_in[8];
    const float* bhhf = (const float*)d_in[9];
    const float* Wihb = (const float*)d_in[10];
    const float* Whhb = (const float*)d_in[11];
    const float* bihb = (const float*)d_in[12];
    const float* bhhb = (const float*)d_in[13];
    float* out = (float*)d_out;

    char* ws = (char*)d_ws;
    // ws layout (bytes):
    //   [0)       fslot int32[32][512]                      65536
    //   [65536)   bpos  int32[32][512]                      65536
    //   [131072)  h ping-pong f32[2dir][2par][64][32][4]   131072
    //   [262144)  c checkpoint f32[2dir][64][4][32]         65536
    //   [327680)  flags: 128 slots x 128 B                  16384
    //   [393216)  xg f32[2dir][Tc][1024][32]           Tc*262144
    int*   fslot = (int*)(ws);
    int*   bpos  = (int*)(ws + 65536);
    float* hbuf  = (float*)(ws + 131072);
    float* cbuf  = (float*)(ws + 262144);
    int*   barr  = (int*)(ws + 327680);
    float* xg    = (float*)(ws + 393216);
    (void)in_sizes; (void)n_in; (void)out_size;

    size_t avail = (ws_size > 393216) ? ws_size - 393216 : 0;
    int Tc = 1;
    for (int c = 512; c >= 1; c >>= 1)
        if ((size_t)c * 262144 <= avail) { Tc = c; break; }

    slots_kernel<<<1, 64, 0, stream>>>(fm, bm, fslot, bpos);

    for (int t0 = 0; t0 < T_; t0 += Tc) {
        dim3 g(16, Tc, 2);
        xg_gemm<<<g, 256, 0, stream>>>(inputs, seqlen, emb, Wihf, Wihb,
                                       bihf, bhhf, bihb, bhhb, xg, t0, Tc);
        hipMemsetAsync(barr, 0, 16384, stream);   // reset flags for this chunk
        persist_rec<<<128, 512, 0, stream>>>(xg, seqlen, Whhf, Whhb,
                                             fslot, bpos, hbuf, cbuf, barr, out, t0, Tc);
    }
}

// Round 7
// 4087.493 us; speedup vs baseline: 2.4408x; 1.3445x over previous
//
#include <hip/hip_runtime.h>
#include <hip/hip_bf16.h>

#define B_   32
#define T_   512
#define E_   300
#define H_   256
#define OUT_ 256
#define EPAD 304
#define GROWP 293   // gbuf row stride; row=unit*4+gate -> banks 5*rg+4*bgr: conflict-free

typedef unsigned long long u64;

// ---------------------------------------------------------------------------
// Slot tables, LDS-staged: fslot[b][t] = fwd slot (else -1), bpos = OUT-1-slot.
// Dtype detect: first 512 bytes of fm hold 256 nonzero bytes iff bool
// (row0 has exactly 256 True); if int32, <=128 nonzero bytes.
// ---------------------------------------------------------------------------
__global__ __launch_bounds__(64) void slots_kernel(
    const unsigned char* __restrict__ fm, const unsigned char* __restrict__ bm,
    int* __restrict__ fslot, int* __restrict__ bpos)
{
    __shared__ unsigned char fL[B_ * T_];   // 16 KB
    __shared__ unsigned char bL[B_ * T_];   // 16 KB
    const int tid = threadIdx.x;

    // detect: count nonzero bytes in fm[0..511]
    const unsigned int* fw = (const unsigned int*)fm;
    int cnt = 0;
    for (int i = tid; i < 128; i += 64) {
        unsigned int v = fw[i];
        cnt += ((v & 0xFFu) != 0) + ((v & 0xFF00u) != 0)
             + ((v & 0xFF0000u) != 0) + ((v >> 24) != 0);
    }
#pragma unroll
    for (int off = 32; off; off >>= 1) cnt += __shfl_down(cnt, off, 64);
    bool isbool = __shfl(cnt, 0, 64) > 128;

    if (isbool) {
        for (int i = tid; i < B_ * T_ / 4; i += 64) {
            ((unsigned int*)fL)[i] = ((const unsigned int*)fm)[i];
            ((unsigned int*)bL)[i] = ((const unsigned int*)bm)[i];
        }
    } else {
        const unsigned int* bw = (const unsigned int*)bm;
        for (int i = tid; i < B_ * T_; i += 64) {
            fL[i] = fw[i] != 0;
            bL[i] = bw[i] != 0;
        }
    }
    __syncthreads();

    if (tid < B_) {
        int jf = 0, jb = 0;
        for (int t = 0; t < T_; ++t) {
            bool f = fL[tid * T_ + t] != 0;
            bool g = bL[tid * T_ + t] != 0;
            fslot[tid * T_ + t] = f ? (jf++) : -1;
            bpos [tid * T_ + t] = g ? (OUT_ - 1 - (jb++)) : -1;
        }
    }
}

// ---------------------------------------------------------------------------
// xg GEMM (unchanged, known good).
// ---------------------------------------------------------------------------
__global__ __launch_bounds__(256) void xg_gemm(
    const int* __restrict__ inputs, const int* __restrict__ seqlen,
    const float* __restrict__ emb,
    const float* __restrict__ Wihf, const float* __restrict__ Wihb,
    const float* __restrict__ bihf, const float* __restrict__ bhhf,
    const float* __restrict__ bihb, const float* __restrict__ bhhb,
    float* __restrict__ xg, int t0, int TcMax)
{
    const int tc  = blockIdx.y;
    const int t   = t0 + tc;
    const int dir = blockIdx.z;
    const int rblk = blockIdx.x * 64;

    __shared__ float eL[B_][EPAD];

    for (int idx = threadIdx.x; idx < B_ * 75; idx += 256) {
        int b = idx / 75, q = idx - b * 75;
        int L = seqlen[b];
        int tt = t;
        if (dir) tt = (t < L) ? (L - 1 - t) : t;
        int tok = inputs[b * T_ + tt];
        float4 v = *(const float4*)(emb + (size_t)tok * E_ + q * 4);
        *(float4*)(&eL[b][q * 4]) = v;
    }
    __syncthreads();

    const float* W  = dir ? Wihb : Wihf;
    const float* bi = dir ? bihb : bihf;
    const float* bh = dir ? bhhb : bhhf;

    const int b  = threadIdx.x & 31;
    const int r8 = threadIdx.x >> 5;
    float acc[8];
#pragma unroll
    for (int m = 0; m < 8; ++m) acc[m] = 0.f;

    for (int e = 0; e < E_; e += 4) {
        float4 h4 = *(const float4*)(&eL[b][e]);
#pragma unroll
        for (int m = 0; m < 8; ++m) {
            int row = rblk + r8 + m * 8;
            float4 w4 = *(const float4*)(W + (size_t)row * E_ + e);
            acc[m] += h4.x * w4.x + h4.y * w4.y + h4.z * w4.z + h4.w * w4.w;
        }
    }

    float* outp = xg + (size_t)(dir * TcMax + tc) * (1024 * B_);
#pragma unroll
    for (int m = 0; m < 8; ++m) {
        int row = rblk + r8 + m * 8;
        outp[(size_t)row * B_ + b] = acc[m] + bi[row] + bh[row];
    }
}

// ---------------------------------------------------------------------------
// Persistent recurrence v4: 128 WGs (64/dir) x 512 thr, 4 units/WG.
// W_hh permanently in VGPRs; h is the only LDS-dot input (block-permuted hP,
// conflict-free b128 reads). Cross-WG h travels via LLC-bypass relaxed agent
// atomics (stores AND loads) -> no buffer_wbl2 of dirty lines, no buffer_inv,
// no __threadfence. Flag release's vmcnt orders the bypass h-stores.
// ---------------------------------------------------------------------------
__global__ __launch_bounds__(512, 2) void persist_rec(
    const float* __restrict__ xg, const int* __restrict__ seqlen,
    const float* __restrict__ Whh_f, const float* __restrict__ Whh_b,
    const int* __restrict__ fslot, const int* __restrict__ bpos,
    float* __restrict__ hbuf, float* __restrict__ cbuf,
    int* __restrict__ barr, float* __restrict__ out, int t0, int Tc)
{
    const int wg  = blockIdx.x;          // 0..127
    const int dir = wg >> 6;
    const int wgd = wg & 63;
    const int u0  = wgd * 4;
    const int tid = threadIdx.x;

    // dot-phase mapping
    const int rg  = tid & 3;             // gate 0..3
    const int bgr = (tid >> 2) & 7;      // batch-quad 0..7
    const int kq  = tid >> 5;            // k16-group 0..15

    __shared__ float hP[128 * 68];       // permuted h(t-1), 34.8 KB
    __shared__ float gbuf[16 * GROWP];   // partials [unit*4+gate][b][kq2]
    __shared__ int   sL[B_];

    // W_hh slice -> registers, once
    const float* Whh = dir ? Whh_b : Whh_f;
    float w[4][16];
#pragma unroll
    for (int r = 0; r < 4; ++r) {
        const float* wr = Whh + (size_t)(rg * H_ + u0 + r) * H_ + kq * 16;
#pragma unroll
        for (int q = 0; q < 4; ++q) {
            float4 v = *(const float4*)(wr + q * 4);
            w[r][q * 4 + 0] = v.x; w[r][q * 4 + 1] = v.y;
            w[r][q * 4 + 2] = v.z; w[r][q * 4 + 3] = v.w;
        }
    }
    if (tid < B_) sL[tid] = seqlen[tid];
    __syncthreads();

    const int ul = (tid >> 5) & 3, bb = tid & 31;   // epilogue mapping (tid<128)
    float c_reg = 0.f;
    if (t0 > 0 && tid < 128)
        c_reg = cbuf[(size_t)(dir * 64 + wgd) * 128 + ul * 32 + bb];

    float xgv0 = 0.f, xgv1 = 0.f, xgv2 = 0.f, xgv3 = 0.f;
    if (tid < 128) {
        const float* xp = xg + (size_t)(dir * Tc) * 32768 + (u0 + ul) * 32 + bb;
        xgv0 = xp[0];
        xgv1 = xp[256 * 32];
        xgv2 = xp[512 * 32];
        xgv3 = xp[768 * 32];
    }

    int* myflag = barr + (size_t)wg * 32;            // 128B-spaced own slot

    for (int tc = 0; tc < Tc; ++tc) {
        const int t = t0 + tc;

        // prefetch next step's xg before the wait (independent loads)
        float xgn0 = 0.f, xgn1 = 0.f, xgn2 = 0.f, xgn3 = 0.f;
        if (tc + 1 < Tc && tid < 128) {
            const float* xp = xg + (size_t)(dir * Tc + tc + 1) * 32768 + (u0 + ul) * 32 + bb;
            xgn0 = xp[0];
            xgn1 = xp[256 * 32];
            xgn2 = xp[512 * 32];
            xgn3 = xp[768 * 32];
        }

        if (tc > 0) {
            if (tid < 64) {   // parallel poll: lane <-> flag of this dir
                const int* fp = barr + (size_t)(dir * 64 + tid) * 32;
                while (!__all(__hip_atomic_load(fp, __ATOMIC_RELAXED,
                                                __HIP_MEMORY_SCOPE_AGENT) >= tc))
                    __builtin_amdgcn_s_sleep(1);
                // no fence: h loads below are LLC-bypass atomics (never stale);
                // __syncthreads provides compiler/control ordering.
            }
            __syncthreads();
        }

        // stage h(t-1) into permuted hP via LLC-bypass 8B atomic loads
        if (t > 0) {
            const u64* hp64 = (const u64*)(hbuf +
                (size_t)(dir * 2 + ((t - 1) & 1)) * (64 * 32 * 4));
#pragma unroll
            for (int i = 0; i < 8; ++i) {
                int g = tid + 512 * i;           // 0..4095
                u64 q = __hip_atomic_load(hp64 + g, __ATOMIC_RELAXED,
                                          __HIP_MEMORY_SCOPE_AGENT);
                int f4 = g >> 1, jp = g & 1;
                int k4 = f4 >> 5, b = f4 & 31;
                int base = ((k4 >> 2) * 8 + (b >> 2)) * 68 + (k4 & 3) * 16 + (b & 3);
                union { u64 u; float f[2]; } cv; cv.u = q;
                hP[base + 8 * jp]     = cv.f[0];
                hP[base + 8 * jp + 4] = cv.f[1];
            }
        }
        __syncthreads();

        // dot: acc[r][bi] over this thread's 16 k's (W from registers)
        float acc[4][4];
#pragma unroll
        for (int r = 0; r < 4; ++r)
#pragma unroll
            for (int bi = 0; bi < 4; ++bi) acc[r][bi] = 0.f;

        if (t > 0) {
            const float* hblk = &hP[(kq * 8 + bgr) * 68];
#pragma unroll
            for (int kk = 0; kk < 16; ++kk) {
                float4 h4 = *(const float4*)(hblk + kk * 4);
#pragma unroll
                for (int r = 0; r < 4; ++r) {
                    acc[r][0] += w[r][kk] * h4.x;
                    acc[r][1] += w[r][kk] * h4.y;
                    acc[r][2] += w[r][kk] * h4.z;
                    acc[r][3] += w[r][kk] * h4.w;
                }
            }
        }

        // fold kq-pairs (lanes 32 apart, same wave)
#pragma unroll
        for (int r = 0; r < 4; ++r)
#pragma unroll
            for (int bi = 0; bi < 4; ++bi)
                acc[r][bi] += __shfl_xor(acc[r][bi], 32, 64);

        if (((tid >> 5) & 1) == 0) {
            const int kq2 = kq >> 1;             // 0..7
#pragma unroll
            for (int r = 0; r < 4; ++r)          // row = unit*4 + gate
#pragma unroll
                for (int bi = 0; bi < 4; ++bi)
                    gbuf[(r * 4 + rg) * GROWP + (bgr * 4 + bi) * 9 + kq2] = acc[r][bi];
        }
        __syncthreads();

        // epilogue: thread (ul, bb) handles unit u0+ul, batch bb
        if (tid < 128) {
            const int u = u0 + ul;
            float hnew;
            if (t < sL[bb]) {
                float gi = xgv0, gf = xgv1, gg = xgv2, go = xgv3;
#pragma unroll
                for (int q = 0; q < 8; ++q) {
                    gi += gbuf[(ul * 4 + 0) * GROWP + bb * 9 + q];
                    gf += gbuf[(ul * 4 + 1) * GROWP + bb * 9 + q];
                    gg += gbuf[(ul * 4 + 2) * GROWP + bb * 9 + q];
                    go += gbuf[(ul * 4 + 3) * GROWP + bb * 9 + q];
                }
                float si = 1.f / (1.f + expf(-gi));
                float sf = 1.f / (1.f + expf(-gf));
                float so = 1.f / (1.f + expf(-go));
                c_reg = sf * c_reg + si * tanhf(gg);
                hnew  = so * tanhf(c_reg);
                if (dir == 0) {
                    int j = fslot[bb * T_ + t];
                    if (j >= 0)
                        __hip_atomic_store(&out[((size_t)bb * OUT_ + j) * 512 + u],
                                           hnew, __ATOMIC_RELAXED,
                                           __HIP_MEMORY_SCOPE_AGENT);
                } else {
                    int p = bpos[bb * T_ + t];
                    if (p >= 0)
                        __hip_atomic_store(&out[((size_t)bb * OUT_ + p) * 512 + 256 + u],
                                           hnew, __ATOMIC_RELAXED,
                                           __HIP_MEMORY_SCOPE_AGENT);
                }
            } else {
                hnew = hP[((u >> 4) * 8 + (bb >> 2)) * 68 + (u & 15) * 4 + (bb & 3)];
            }
            float* hn = hbuf + (size_t)(dir * 2 + (t & 1)) * (64 * 32 * 4);
            __hip_atomic_store(&hn[(wgd * 32 + bb) * 4 + ul], hnew,
                               __ATOMIC_RELAXED, __HIP_MEMORY_SCOPE_AGENT);
        }
        xgv0 = xgn0; xgv1 = xgn1; xgv2 = xgn2; xgv3 = xgn3;
        __syncthreads();   // each wave drains its own (bypass) h stores here

        if (tc + 1 < Tc && tid == 0)
            __hip_atomic_store(myflag, tc + 1, __ATOMIC_RELEASE,
                               __HIP_MEMORY_SCOPE_AGENT);
    }

    if (tid < 128)   // checkpoint c for next chunk
        cbuf[(size_t)(dir * 64 + wgd) * 128 + ul * 32 + bb] = c_reg;
}

// ---------------------------------------------------------------------------
extern "C" void kernel_launch(void* const* d_in, const int* in_sizes, int n_in,
                              void* d_out, int out_size, void* d_ws, size_t ws_size,
                              hipStream_t stream) {
    const int*           inputs = (const int*)d_in[0];
    const int*           seqlen = (const int*)d_in[1];
    const unsigned char* fm     = (const unsigned char*)d_in[2];
    const unsigned char* bm     = (const unsigned char*)d_in[3];
    // d_in[4] = out_seq_length (== 256, hardcoded)
    const float* emb  = (const float*)d_in[5];
    const float* Wihf = (const float*)d_in[6];
    const float* Whhf = (const float*)d_in[7];
    const float* bihf = (const float*)d_in[8];
    const float* bhhf = (const float*)d_in[9];
    const float* Wihb = (const float*)d_in[10];
    const float* Whhb = (const float*)d_in[11];
    const float* bihb = (const float*)d_in[12];
    const float* bhhb = (const float*)d_in[13];
    float* out = (float*)d_out;

    char* ws = (char*)d_ws;
    // ws layout (bytes):
    //   [0)       fslot int32[32][512]                      65536
    //   [65536)   bpos  int32[32][512]                      65536
    //   [131072)  h ping-pong f32[2dir][2par][64][32][4]   131072
    //   [262144)  c checkpoint f32[2dir][64][4][32]         65536
    //   [327680)  flags: 128 slots x 128 B                  16384
    //   [393216)  xg f32[2dir][Tc][1024][32]           Tc*262144
    int*   fslot = (int*)(ws);
    int*   bpos  = (int*)(ws + 65536);
    float* hbuf  = (float*)(ws + 131072);
    float* cbuf  = (float*)(ws + 262144);
    int*   barr  = (int*)(ws + 327680);
    float* xg    = (float*)(ws + 393216);
    (void)in_sizes; (void)n_in; (void)out_size;

    size_t avail = (ws_size > 393216) ? ws_size - 393216 : 0;
    int Tc = 1;
    for (int c = 512; c >= 1; c >>= 1)
        if ((size_t)c * 262144 <= avail) { Tc = c; break; }

    slots_kernel<<<1, 64, 0, stream>>>(fm, bm, fslot, bpos);

    for (int t0 = 0; t0 < T_; t0 += Tc) {
        dim3 g(16, Tc, 2);
        xg_gemm<<<g, 256, 0, stream>>>(inputs, seqlen, emb, Wihf, Wihb,
                                       bihf, bhhf, bihb, bhhb, xg, t0, Tc);
        hipMemsetAsync(barr, 0, 16384, stream);   // reset flags for this chunk
        persist_rec<<<128, 512, 0, stream>>>(xg, seqlen, Whhf, Whhb,
                                             fslot, bpos, hbuf, cbuf, barr, out, t0, Tc);
    }
}

// Round 8
// 2731.703 us; speedup vs baseline: 3.6522x; 1.4963x over previous
//
#include <hip/hip_runtime.h>
#include <hip/hip_bf16.h>

#define B_   32
#define T_   512
#define E_   300
#define H_   256
#define OUT_ 256
#define ECH  100    // gemm e-chunk (3 x 100 = 300)
#define GROWP 293   // gbuf row stride; row=unit*4+gate -> banks 5*rg+4*bgr: conflict-free

typedef unsigned long long u64;

// ---------------------------------------------------------------------------
// Slot tables, LDS-staged (unchanged from r7).
// ---------------------------------------------------------------------------
__global__ __launch_bounds__(64) void slots_kernel(
    const unsigned char* __restrict__ fm, const unsigned char* __restrict__ bm,
    int* __restrict__ fslot, int* __restrict__ bpos)
{
    __shared__ unsigned char fL[B_ * T_];   // 16 KB
    __shared__ unsigned char bL[B_ * T_];   // 16 KB
    const int tid = threadIdx.x;

    const unsigned int* fw = (const unsigned int*)fm;
    int cnt = 0;
    for (int i = tid; i < 128; i += 64) {
        unsigned int v = fw[i];
        cnt += ((v & 0xFFu) != 0) + ((v & 0xFF00u) != 0)
             + ((v & 0xFF0000u) != 0) + ((v >> 24) != 0);
    }
#pragma unroll
    for (int off = 32; off; off >>= 1) cnt += __shfl_down(cnt, off, 64);
    bool isbool = __shfl(cnt, 0, 64) > 128;

    if (isbool) {
        for (int i = tid; i < B_ * T_ / 4; i += 64) {
            ((unsigned int*)fL)[i] = ((const unsigned int*)fm)[i];
            ((unsigned int*)bL)[i] = ((const unsigned int*)bm)[i];
        }
    } else {
        const unsigned int* bw = (const unsigned int*)bm;
        for (int i = tid; i < B_ * T_; i += 64) {
            fL[i] = fw[i] != 0;
            bL[i] = bw[i] != 0;
        }
    }
    __syncthreads();

    if (tid < B_) {
        int jf = 0, jb = 0;
        for (int t = 0; t < T_; ++t) {
            bool f = fL[tid * T_ + t] != 0;
            bool g = bL[tid * T_ + t] != 0;
            fslot[tid * T_ + t] = f ? (jf++) : -1;
            bpos [tid * T_ + t] = g ? (OUT_ - 1 - (jb++)) : -1;
        }
    }
}

// ---------------------------------------------------------------------------
// xg GEMM v2: 4 time-steps per block -> W_ih fragments loaded once into
// registers serve 4 t's. eL e-chunked [4][32][100]: stride-100 column b128
// reads are 4-way (1.58x) instead of the old [b][304]'s 16-way (5.7x).
// grid (16 row-blocks, Tc/4, 2 dirs), block 256.
// ---------------------------------------------------------------------------
__global__ __launch_bounds__(256) void xg_gemm(
    const int* __restrict__ inputs, const int* __restrict__ seqlen,
    const float* __restrict__ emb,
    const float* __restrict__ Wihf, const float* __restrict__ Wihb,
    const float* __restrict__ bihf, const float* __restrict__ bhhf,
    const float* __restrict__ bihb, const float* __restrict__ bhhb,
    float* __restrict__ xg, int t0, int TcMax)
{
    const int tg   = blockIdx.y;         // group of 4 consecutive t
    const int dir  = blockIdx.z;
    const int rblk = blockIdx.x * 64;
    const int tid  = threadIdx.x;

    __shared__ float eL[4][B_][ECH];     // 51.2 KB
    __shared__ int   tokS[4][B_];

    if (tid < 128) {
        int t4 = tid >> 5, b = tid & 31;
        int t = t0 + tg * 4 + t4;
        int L = seqlen[b];
        int tt = t;
        if (dir) tt = (t < L) ? (L - 1 - t) : t;
        tokS[t4][b] = inputs[b * T_ + tt];
    }

    const float* W = dir ? Wihb : Wihf;
    const int b  = tid & 31;
    const int r8 = tid >> 5;

    float acc[4][8];
#pragma unroll
    for (int t4 = 0; t4 < 4; ++t4)
#pragma unroll
        for (int m = 0; m < 8; ++m) acc[t4][m] = 0.f;

    for (int ec = 0; ec < 3; ++ec) {
        __syncthreads();   // tokS ready (ec=0) / eL consumed (ec>0)
        // stage 4t x 32b x 25 float4 = 3200 float4
        for (int idx = tid; idx < 3200; idx += 256) {
            int q  = idx % 25;
            int bb = (idx / 25) & 31;
            int t4 = idx / (25 * 32);
            const float* erow = emb + (size_t)tokS[t4][bb] * E_ + ec * ECH;
            *(float4*)&eL[t4][bb][q * 4] = *(const float4*)(erow + q * 4);
        }
        __syncthreads();

        for (int e4 = 0; e4 < 25; ++e4) {
            float4 w4[8];
#pragma unroll
            for (int m = 0; m < 8; ++m)
                w4[m] = *(const float4*)(W + (size_t)(rblk + r8 + m * 8) * E_
                                         + ec * ECH + e4 * 4);
#pragma unroll
            for (int t4 = 0; t4 < 4; ++t4) {
                float4 h4 = *(const float4*)&eL[t4][b][e4 * 4];
#pragma unroll
                for (int m = 0; m < 8; ++m)
                    acc[t4][m] += h4.x * w4[m].x + h4.y * w4[m].y
                                + h4.z * w4[m].z + h4.w * w4[m].w;
            }
        }
    }

    const float* bi = dir ? bihb : bihf;
    const float* bh = dir ? bhhb : bhhf;
#pragma unroll
    for (int t4 = 0; t4 < 4; ++t4) {
        float* outp = xg + (size_t)(dir * TcMax + tg * 4 + t4) * (1024 * B_);
#pragma unroll
        for (int m = 0; m < 8; ++m) {
            int row = rblk + r8 + m * 8;
            outp[(size_t)row * B_ + b] = acc[t4][m] + bi[row] + bh[row];
        }
    }
}

// ---------------------------------------------------------------------------
// Persistent recurrence v5: identical to r7 except the flag store is RELAXED.
// Rationale: __syncthreads() forces each wave's vmcnt(0) before s_barrier, so
// all bypass h-stores have completed at the coherence point before tid 0
// issues the flag store. RELEASE added a buffer_wbl2 (full L2 writeback walk)
// to every step's critical path for no additional guarantee.
// ---------------------------------------------------------------------------
__global__ __launch_bounds__(512, 2) void persist_rec(
    const float* __restrict__ xg, const int* __restrict__ seqlen,
    const float* __restrict__ Whh_f, const float* __restrict__ Whh_b,
    const int* __restrict__ fslot, const int* __restrict__ bpos,
    float* __restrict__ hbuf, float* __restrict__ cbuf,
    int* __restrict__ barr, float* __restrict__ out, int t0, int Tc)
{
    const int wg  = blockIdx.x;          // 0..127
    const int dir = wg >> 6;
    const int wgd = wg & 63;
    const int u0  = wgd * 4;
    const int tid = threadIdx.x;

    const int rg  = tid & 3;             // gate 0..3
    const int bgr = (tid >> 2) & 7;      // batch-quad 0..7
    const int kq  = tid >> 5;            // k16-group 0..15

    __shared__ float hP[128 * 68];       // permuted h(t-1), 34.8 KB
    __shared__ float gbuf[16 * GROWP];   // partials [unit*4+gate][b][kq2]
    __shared__ int   sL[B_];

    const float* Whh = dir ? Whh_b : Whh_f;
    float w[4][16];
#pragma unroll
    for (int r = 0; r < 4; ++r) {
        const float* wr = Whh + (size_t)(rg * H_ + u0 + r) * H_ + kq * 16;
#pragma unroll
        for (int q = 0; q < 4; ++q) {
            float4 v = *(const float4*)(wr + q * 4);
            w[r][q * 4 + 0] = v.x; w[r][q * 4 + 1] = v.y;
            w[r][q * 4 + 2] = v.z; w[r][q * 4 + 3] = v.w;
        }
    }
    if (tid < B_) sL[tid] = seqlen[tid];
    __syncthreads();

    const int ul = (tid >> 5) & 3, bb = tid & 31;   // epilogue mapping (tid<128)
    float c_reg = 0.f;
    if (t0 > 0 && tid < 128)
        c_reg = cbuf[(size_t)(dir * 64 + wgd) * 128 + ul * 32 + bb];

    float xgv0 = 0.f, xgv1 = 0.f, xgv2 = 0.f, xgv3 = 0.f;
    if (tid < 128) {
        const float* xp = xg + (size_t)(dir * Tc) * 32768 + (u0 + ul) * 32 + bb;
        xgv0 = xp[0];
        xgv1 = xp[256 * 32];
        xgv2 = xp[512 * 32];
        xgv3 = xp[768 * 32];
    }

    int* myflag = barr + (size_t)wg * 32;            // 128B-spaced own slot

    for (int tc = 0; tc < Tc; ++tc) {
        const int t = t0 + tc;

        float xgn0 = 0.f, xgn1 = 0.f, xgn2 = 0.f, xgn3 = 0.f;
        if (tc + 1 < Tc && tid < 128) {
            const float* xp = xg + (size_t)(dir * Tc + tc + 1) * 32768 + (u0 + ul) * 32 + bb;
            xgn0 = xp[0];
            xgn1 = xp[256 * 32];
            xgn2 = xp[512 * 32];
            xgn3 = xp[768 * 32];
        }

        if (tc > 0) {
            if (tid < 64) {   // parallel poll: lane <-> flag of this dir
                const int* fp = barr + (size_t)(dir * 64 + tid) * 32;
                while (!__all(__hip_atomic_load(fp, __ATOMIC_RELAXED,
                                                __HIP_MEMORY_SCOPE_AGENT) >= tc))
                    __builtin_amdgcn_s_sleep(1);
                // no fence needed: h loads below are LLC-bypass atomics.
            }
            __syncthreads();
        }

        // stage h(t-1) into permuted hP via LLC-bypass 8B atomic loads
        if (t > 0) {
            const u64* hp64 = (const u64*)(hbuf +
                (size_t)(dir * 2 + ((t - 1) & 1)) * (64 * 32 * 4));
#pragma unroll
            for (int i = 0; i < 8; ++i) {
                int g = tid + 512 * i;           // 0..4095
                u64 q = __hip_atomic_load(hp64 + g, __ATOMIC_RELAXED,
                                          __HIP_MEMORY_SCOPE_AGENT);
                int f4 = g >> 1, jp = g & 1;
                int k4 = f4 >> 5, b = f4 & 31;
                int base = ((k4 >> 2) * 8 + (b >> 2)) * 68 + (k4 & 3) * 16 + (b & 3);
                union { u64 u; float f[2]; } cv; cv.u = q;
                hP[base + 8 * jp]     = cv.f[0];
                hP[base + 8 * jp + 4] = cv.f[1];
            }
        }
        __syncthreads();

        float acc[4][4];
#pragma unroll
        for (int r = 0; r < 4; ++r)
#pragma unroll
            for (int bi = 0; bi < 4; ++bi) acc[r][bi] = 0.f;

        if (t > 0) {
            const float* hblk = &hP[(kq * 8 + bgr) * 68];
#pragma unroll
            for (int kk = 0; kk < 16; ++kk) {
                float4 h4 = *(const float4*)(hblk + kk * 4);
#pragma unroll
                for (int r = 0; r < 4; ++r) {
                    acc[r][0] += w[r][kk] * h4.x;
                    acc[r][1] += w[r][kk] * h4.y;
                    acc[r][2] += w[r][kk] * h4.z;
                    acc[r][3] += w[r][kk] * h4.w;
                }
            }
        }

#pragma unroll
        for (int r = 0; r < 4; ++r)
#pragma unroll
            for (int bi = 0; bi < 4; ++bi)
                acc[r][bi] += __shfl_xor(acc[r][bi], 32, 64);

        if (((tid >> 5) & 1) == 0) {
            const int kq2 = kq >> 1;             // 0..7
#pragma unroll
            for (int r = 0; r < 4; ++r)          // row = unit*4 + gate
#pragma unroll
                for (int bi = 0; bi < 4; ++bi)
                    gbuf[(r * 4 + rg) * GROWP + (bgr * 4 + bi) * 9 + kq2] = acc[r][bi];
        }
        __syncthreads();

        if (tid < 128) {
            const int u = u0 + ul;
            float hnew;
            if (t < sL[bb]) {
                float gi = xgv0, gf = xgv1, gg = xgv2, go = xgv3;
#pragma unroll
                for (int q = 0; q < 8; ++q) {
                    gi += gbuf[(ul * 4 + 0) * GROWP + bb * 9 + q];
                    gf += gbuf[(ul * 4 + 1) * GROWP + bb * 9 + q];
                    gg += gbuf[(ul * 4 + 2) * GROWP + bb * 9 + q];
                    go += gbuf[(ul * 4 + 3) * GROWP + bb * 9 + q];
                }
                float si = 1.f / (1.f + expf(-gi));
                float sf = 1.f / (1.f + expf(-gf));
                float so = 1.f / (1.f + expf(-go));
                c_reg = sf * c_reg + si * tanhf(gg);
                hnew  = so * tanhf(c_reg);
                if (dir == 0) {
                    int j = fslot[bb * T_ + t];
                    if (j >= 0)
                        __hip_atomic_store(&out[((size_t)bb * OUT_ + j) * 512 + u],
                                           hnew, __ATOMIC_RELAXED,
                                           __HIP_MEMORY_SCOPE_AGENT);
                } else {
                    int p = bpos[bb * T_ + t];
                    if (p >= 0)
                        __hip_atomic_store(&out[((size_t)bb * OUT_ + p) * 512 + 256 + u],
                                           hnew, __ATOMIC_RELAXED,
                                           __HIP_MEMORY_SCOPE_AGENT);
                }
            } else {
                hnew = hP[((u >> 4) * 8 + (bb >> 2)) * 68 + (u & 15) * 4 + (bb & 3)];
            }
            float* hn = hbuf + (size_t)(dir * 2 + (t & 1)) * (64 * 32 * 4);
            __hip_atomic_store(&hn[(wgd * 32 + bb) * 4 + ul], hnew,
                               __ATOMIC_RELAXED, __HIP_MEMORY_SCOPE_AGENT);
        }
        xgv0 = xgn0; xgv1 = xgn1; xgv2 = xgn2; xgv3 = xgn3;
        __syncthreads();   // per-wave vmcnt(0) before s_barrier: h stores done

        if (tc + 1 < Tc && tid == 0)
            __hip_atomic_store(myflag, tc + 1, __ATOMIC_RELAXED,   // r8: was RELEASE
                               __HIP_MEMORY_SCOPE_AGENT);
    }

    if (tid < 128)   // checkpoint c for next chunk
        cbuf[(size_t)(dir * 64 + wgd) * 128 + ul * 32 + bb] = c_reg;
}

// ---------------------------------------------------------------------------
extern "C" void kernel_launch(void* const* d_in, const int* in_sizes, int n_in,
                              void* d_out, int out_size, void* d_ws, size_t ws_size,
                              hipStream_t stream) {
    const int*           inputs = (const int*)d_in[0];
    const int*           seqlen = (const int*)d_in[1];
    const unsigned char* fm     = (const unsigned char*)d_in[2];
    const unsigned char* bm     = (const unsigned char*)d_in[3];
    // d_in[4] = out_seq_length (== 256, hardcoded)
    const float* emb  = (const float*)d_in[5];
    const float* Wihf = (const float*)d_in[6];
    const float* Whhf = (const float*)d_in[7];
    const float* bihf = (const float*)d_in[8];
    const float* bhhf = (const float*)d_in[9];
    const float* Wihb = (const float*)d_in[10];
    const float* Whhb = (const float*)d_in[11];
    const float* bihb = (const float*)d_in[12];
    const float* bhhb = (const float*)d_in[13];
    float* out = (float*)d_out;

    char* ws = (char*)d_ws;
    // ws layout (bytes):
    //   [0)       fslot int32[32][512]                      65536
    //   [65536)   bpos  int32[32][512]                      65536
    //   [131072)  h ping-pong f32[2dir][2par][64][32][4]   131072
    //   [262144)  c checkpoint f32[2dir][64][4][32]         65536
    //   [327680)  flags: 128 slots x 128 B                  16384
    //   [393216)  xg f32[2dir][Tc][1024][32]           Tc*262144
    int*   fslot = (int*)(ws);
    int*   bpos  = (int*)(ws + 65536);
    float* hbuf  = (float*)(ws + 131072);
    float* cbuf  = (float*)(ws + 262144);
    int*   barr  = (int*)(ws + 327680);
    float* xg    = (float*)(ws + 393216);
    (void)in_sizes; (void)n_in; (void)out_size;

    size_t avail = (ws_size > 393216) ? ws_size - 393216 : 0;
    int Tc = 4;
    for (int c = 512; c >= 4; c >>= 1)
        if ((size_t)c * 262144 <= avail) { Tc = c; break; }

    slots_kernel<<<1, 64, 0, stream>>>(fm, bm, fslot, bpos);

    for (int t0 = 0; t0 < T_; t0 += Tc) {
        dim3 g(16, Tc / 4, 2);
        xg_gemm<<<g, 256, 0, stream>>>(inputs, seqlen, emb, Wihf, Wihb,
                                       bihf, bhhf, bihb, bhhb, xg, t0, Tc);
        hipMemsetAsync(barr, 0, 16384, stream);   // reset flags for this chunk
        persist_rec<<<128, 512, 0, stream>>>(xg, seqlen, Whhf, Whhb,
                                             fslot, bpos, hbuf, cbuf, barr, out, t0, Tc);
    }
}

// Round 9
// 2323.994 us; speedup vs baseline: 4.2929x; 1.1754x over previous
//
#include <hip/hip_runtime.h>
#include <hip/hip_bf16.h>

#define B_   32
#define T_   512
#define E_   300
#define H_   256
#define OUT_ 256
#define ECH  100    // gemm e-chunk (3 x 100 = 300)
#define GROWP 293   // gbuf row stride; row=unit*4+gate -> banks 5*rg+4*bgr: conflict-free

typedef unsigned long long u64;

// ---------------------------------------------------------------------------
// Slot tables, LDS-staged (unchanged).
// ---------------------------------------------------------------------------
__global__ __launch_bounds__(64) void slots_kernel(
    const unsigned char* __restrict__ fm, const unsigned char* __restrict__ bm,
    int* __restrict__ fslot, int* __restrict__ bpos)
{
    __shared__ unsigned char fL[B_ * T_];   // 16 KB
    __shared__ unsigned char bL[B_ * T_];   // 16 KB
    const int tid = threadIdx.x;

    const unsigned int* fw = (const unsigned int*)fm;
    int cnt = 0;
    for (int i = tid; i < 128; i += 64) {
        unsigned int v = fw[i];
        cnt += ((v & 0xFFu) != 0) + ((v & 0xFF00u) != 0)
             + ((v & 0xFF0000u) != 0) + ((v >> 24) != 0);
    }
#pragma unroll
    for (int off = 32; off; off >>= 1) cnt += __shfl_down(cnt, off, 64);
    bool isbool = __shfl(cnt, 0, 64) > 128;

    if (isbool) {
        for (int i = tid; i < B_ * T_ / 4; i += 64) {
            ((unsigned int*)fL)[i] = ((const unsigned int*)fm)[i];
            ((unsigned int*)bL)[i] = ((const unsigned int*)bm)[i];
        }
    } else {
        const unsigned int* bw = (const unsigned int*)bm;
        for (int i = tid; i < B_ * T_; i += 64) {
            fL[i] = fw[i] != 0;
            bL[i] = bw[i] != 0;
        }
    }
    __syncthreads();

    if (tid < B_) {
        int jf = 0, jb = 0;
        for (int t = 0; t < T_; ++t) {
            bool f = fL[tid * T_ + t] != 0;
            bool g = bL[tid * T_ + t] != 0;
            fslot[tid * T_ + t] = f ? (jf++) : -1;
            bpos [tid * T_ + t] = g ? (OUT_ - 1 - (jb++)) : -1;
        }
    }
}

// ---------------------------------------------------------------------------
// xg GEMM v2 (unchanged from r8: 4 t's per block, W in regs, e-chunked eL).
// ---------------------------------------------------------------------------
__global__ __launch_bounds__(256) void xg_gemm(
    const int* __restrict__ inputs, const int* __restrict__ seqlen,
    const float* __restrict__ emb,
    const float* __restrict__ Wihf, const float* __restrict__ Wihb,
    const float* __restrict__ bihf, const float* __restrict__ bhhf,
    const float* __restrict__ bihb, const float* __restrict__ bhhb,
    float* __restrict__ xg, int t0, int TcMax)
{
    const int tg   = blockIdx.y;         // group of 4 consecutive t
    const int dir  = blockIdx.z;
    const int rblk = blockIdx.x * 64;
    const int tid  = threadIdx.x;

    __shared__ float eL[4][B_][ECH];     // 51.2 KB
    __shared__ int   tokS[4][B_];

    if (tid < 128) {
        int t4 = tid >> 5, b = tid & 31;
        int t = t0 + tg * 4 + t4;
        int L = seqlen[b];
        int tt = t;
        if (dir) tt = (t < L) ? (L - 1 - t) : t;
        tokS[t4][b] = inputs[b * T_ + tt];
    }

    const float* W = dir ? Wihb : Wihf;
    const int b  = tid & 31;
    const int r8 = tid >> 5;

    float acc[4][8];
#pragma unroll
    for (int t4 = 0; t4 < 4; ++t4)
#pragma unroll
        for (int m = 0; m < 8; ++m) acc[t4][m] = 0.f;

    for (int ec = 0; ec < 3; ++ec) {
        __syncthreads();   // tokS ready (ec=0) / eL consumed (ec>0)
        for (int idx = tid; idx < 3200; idx += 256) {
            int q  = idx % 25;
            int bb = (idx / 25) & 31;
            int t4 = idx / (25 * 32);
            const float* erow = emb + (size_t)tokS[t4][bb] * E_ + ec * ECH;
            *(float4*)&eL[t4][bb][q * 4] = *(const float4*)(erow + q * 4);
        }
        __syncthreads();

        for (int e4 = 0; e4 < 25; ++e4) {
            float4 w4[8];
#pragma unroll
            for (int m = 0; m < 8; ++m)
                w4[m] = *(const float4*)(W + (size_t)(rblk + r8 + m * 8) * E_
                                         + ec * ECH + e4 * 4);
#pragma unroll
            for (int t4 = 0; t4 < 4; ++t4) {
                float4 h4 = *(const float4*)&eL[t4][b][e4 * 4];
#pragma unroll
                for (int m = 0; m < 8; ++m)
                    acc[t4][m] += h4.x * w4[m].x + h4.y * w4[m].y
                                + h4.z * w4[m].z + h4.w * w4[m].w;
            }
        }
    }

    const float* bi = dir ? bihb : bihf;
    const float* bh = dir ? bhhb : bhhf;
#pragma unroll
    for (int t4 = 0; t4 < 4; ++t4) {
        float* outp = xg + (size_t)(dir * TcMax + tg * 4 + t4) * (1024 * B_);
#pragma unroll
        for (int m = 0; m < 8; ++m) {
            int row = rblk + r8 + m * 8;
            outp[(size_t)row * B_ + b] = acc[t4][m] + bi[row] + bh[row];
        }
    }
}

// ---------------------------------------------------------------------------
// Persistent recurrence v6. Changes vs r8:
//  (1) h-staging split into LOAD phase (8 bypass loads -> regs, pipelined
//      under one vmcnt chain) then STORE phase (8 LDS writes). r8 interleaved
//      them -> backend serialized 8 x ~700cy LLC round trips per step.
//  (2) flags packed at 4B stride (256B per dir): poll is one coalesced
//      64-lane load instead of a 64-line gather. Stores are plain bypass
//      stores (no RMW), so same-line sharing is harmless.
// ---------------------------------------------------------------------------
__global__ __launch_bounds__(512, 2) void persist_rec(
    const float* __restrict__ xg, const int* __restrict__ seqlen,
    const float* __restrict__ Whh_f, const float* __restrict__ Whh_b,
    const int* __restrict__ fslot, const int* __restrict__ bpos,
    float* __restrict__ hbuf, float* __restrict__ cbuf,
    int* __restrict__ barr, float* __restrict__ out, int t0, int Tc)
{
    const int wg  = blockIdx.x;          // 0..127
    const int dir = wg >> 6;
    const int wgd = wg & 63;
    const int u0  = wgd * 4;
    const int tid = threadIdx.x;

    const int rg  = tid & 3;             // gate 0..3
    const int bgr = (tid >> 2) & 7;      // batch-quad 0..7
    const int kq  = tid >> 5;            // k16-group 0..15

    __shared__ float hP[128 * 68];       // permuted h(t-1), 34.8 KB
    __shared__ float gbuf[16 * GROWP];   // partials [unit*4+gate][b][kq2]
    __shared__ int   sL[B_];

    const float* Whh = dir ? Whh_b : Whh_f;
    float w[4][16];
#pragma unroll
    for (int r = 0; r < 4; ++r) {
        const float* wr = Whh + (size_t)(rg * H_ + u0 + r) * H_ + kq * 16;
#pragma unroll
        for (int q = 0; q < 4; ++q) {
            float4 v = *(const float4*)(wr + q * 4);
            w[r][q * 4 + 0] = v.x; w[r][q * 4 + 1] = v.y;
            w[r][q * 4 + 2] = v.z; w[r][q * 4 + 3] = v.w;
        }
    }
    if (tid < B_) sL[tid] = seqlen[tid];
    __syncthreads();

    const int ul = (tid >> 5) & 3, bb = tid & 31;   // epilogue mapping (tid<128)
    float c_reg = 0.f;
    if (t0 > 0 && tid < 128)
        c_reg = cbuf[(size_t)(dir * 64 + wgd) * 128 + ul * 32 + bb];

    float xgv0 = 0.f, xgv1 = 0.f, xgv2 = 0.f, xgv3 = 0.f;
    if (tid < 128) {
        const float* xp = xg + (size_t)(dir * Tc) * 32768 + (u0 + ul) * 32 + bb;
        xgv0 = xp[0];
        xgv1 = xp[256 * 32];
        xgv2 = xp[512 * 32];
        xgv3 = xp[768 * 32];
    }

    int* myflag = barr + dir * 64 + wgd;             // packed: 4B stride

    for (int tc = 0; tc < Tc; ++tc) {
        const int t = t0 + tc;

        float xgn0 = 0.f, xgn1 = 0.f, xgn2 = 0.f, xgn3 = 0.f;
        if (tc + 1 < Tc && tid < 128) {
            const float* xp = xg + (size_t)(dir * Tc + tc + 1) * 32768 + (u0 + ul) * 32 + bb;
            xgn0 = xp[0];
            xgn1 = xp[256 * 32];
            xgn2 = xp[512 * 32];
            xgn3 = xp[768 * 32];
        }

        if (tc > 0) {
            if (tid < 64) {   // one coalesced 256B poll load per iteration
                const int* fp = barr + dir * 64 + tid;
                while (!__all(__hip_atomic_load(fp, __ATOMIC_RELAXED,
                                                __HIP_MEMORY_SCOPE_AGENT) >= tc))
                    __builtin_amdgcn_s_sleep(1);
            }
            __syncthreads();
        }

        // stage h(t-1): LOAD phase (8 independent bypass loads -> regs)
        u64 hr[8];
        if (t > 0) {
            const u64* hp64 = (const u64*)(hbuf +
                (size_t)(dir * 2 + ((t - 1) & 1)) * (64 * 32 * 4));
#pragma unroll
            for (int i = 0; i < 8; ++i)
                hr[i] = __hip_atomic_load(hp64 + tid + 512 * i, __ATOMIC_RELAXED,
                                          __HIP_MEMORY_SCOPE_AGENT);
            // STORE phase (LDS writes drain the load pipe incrementally)
#pragma unroll
            for (int i = 0; i < 8; ++i) {
                int g = tid + 512 * i;           // 0..4095
                int f4 = g >> 1, jp = g & 1;
                int k4 = f4 >> 5, b = f4 & 31;
                int base = ((k4 >> 2) * 8 + (b >> 2)) * 68 + (k4 & 3) * 16 + (b & 3);
                union { u64 u; float f[2]; } cv; cv.u = hr[i];
                hP[base + 8 * jp]     = cv.f[0];
                hP[base + 8 * jp + 4] = cv.f[1];
            }
        }
        __syncthreads();

        float acc[4][4];
#pragma unroll
        for (int r = 0; r < 4; ++r)
#pragma unroll
            for (int bi = 0; bi < 4; ++bi) acc[r][bi] = 0.f;

        if (t > 0) {
            const float* hblk = &hP[(kq * 8 + bgr) * 68];
#pragma unroll
            for (int kk = 0; kk < 16; ++kk) {
                float4 h4 = *(const float4*)(hblk + kk * 4);
#pragma unroll
                for (int r = 0; r < 4; ++r) {
                    acc[r][0] += w[r][kk] * h4.x;
                    acc[r][1] += w[r][kk] * h4.y;
                    acc[r][2] += w[r][kk] * h4.z;
                    acc[r][3] += w[r][kk] * h4.w;
                }
            }
        }

#pragma unroll
        for (int r = 0; r < 4; ++r)
#pragma unroll
            for (int bi = 0; bi < 4; ++bi)
                acc[r][bi] += __shfl_xor(acc[r][bi], 32, 64);

        if (((tid >> 5) & 1) == 0) {
            const int kq2 = kq >> 1;             // 0..7
#pragma unroll
            for (int r = 0; r < 4; ++r)          // row = unit*4 + gate
#pragma unroll
                for (int bi = 0; bi < 4; ++bi)
                    gbuf[(r * 4 + rg) * GROWP + (bgr * 4 + bi) * 9 + kq2] = acc[r][bi];
        }
        __syncthreads();

        if (tid < 128) {
            const int u = u0 + ul;
            float hnew;
            if (t < sL[bb]) {
                float gi = xgv0, gf = xgv1, gg = xgv2, go = xgv3;
#pragma unroll
                for (int q = 0; q < 8; ++q) {
                    gi += gbuf[(ul * 4 + 0) * GROWP + bb * 9 + q];
                    gf += gbuf[(ul * 4 + 1) * GROWP + bb * 9 + q];
                    gg += gbuf[(ul * 4 + 2) * GROWP + bb * 9 + q];
                    go += gbuf[(ul * 4 + 3) * GROWP + bb * 9 + q];
                }
                float si = 1.f / (1.f + expf(-gi));
                float sf = 1.f / (1.f + expf(-gf));
                float so = 1.f / (1.f + expf(-go));
                c_reg = sf * c_reg + si * tanhf(gg);
                hnew  = so * tanhf(c_reg);
                if (dir == 0) {
                    int j = fslot[bb * T_ + t];
                    if (j >= 0)
                        __hip_atomic_store(&out[((size_t)bb * OUT_ + j) * 512 + u],
                                           hnew, __ATOMIC_RELAXED,
                                           __HIP_MEMORY_SCOPE_AGENT);
                } else {
                    int p = bpos[bb * T_ + t];
                    if (p >= 0)
                        __hip_atomic_store(&out[((size_t)bb * OUT_ + p) * 512 + 256 + u],
                                           hnew, __ATOMIC_RELAXED,
                                           __HIP_MEMORY_SCOPE_AGENT);
                }
            } else {
                hnew = hP[((u >> 4) * 8 + (bb >> 2)) * 68 + (u & 15) * 4 + (bb & 3)];
            }
            float* hn = hbuf + (size_t)(dir * 2 + (t & 1)) * (64 * 32 * 4);
            __hip_atomic_store(&hn[(wgd * 32 + bb) * 4 + ul], hnew,
                               __ATOMIC_RELAXED, __HIP_MEMORY_SCOPE_AGENT);
        }
        xgv0 = xgn0; xgv1 = xgn1; xgv2 = xgn2; xgv3 = xgn3;
        __syncthreads();   // per-wave vmcnt(0) before s_barrier: h stores done

        if (tc + 1 < Tc && tid == 0)
            __hip_atomic_store(myflag, tc + 1, __ATOMIC_RELAXED,
                               __HIP_MEMORY_SCOPE_AGENT);
    }

    if (tid < 128)   // checkpoint c for next chunk
        cbuf[(size_t)(dir * 64 + wgd) * 128 + ul * 32 + bb] = c_reg;
}

// ---------------------------------------------------------------------------
extern "C" void kernel_launch(void* const* d_in, const int* in_sizes, int n_in,
                              void* d_out, int out_size, void* d_ws, size_t ws_size,
                              hipStream_t stream) {
    const int*           inputs = (const int*)d_in[0];
    const int*           seqlen = (const int*)d_in[1];
    const unsigned char* fm     = (const unsigned char*)d_in[2];
    const unsigned char* bm     = (const unsigned char*)d_in[3];
    // d_in[4] = out_seq_length (== 256, hardcoded)
    const float* emb  = (const float*)d_in[5];
    const float* Wihf = (const float*)d_in[6];
    const float* Whhf = (const float*)d_in[7];
    const float* bihf = (const float*)d_in[8];
    const float* bhhf = (const float*)d_in[9];
    const float* Wihb = (const float*)d_in[10];
    const float* Whhb = (const float*)d_in[11];
    const float* bihb = (const float*)d_in[12];
    const float* bhhb = (const float*)d_in[13];
    float* out = (float*)d_out;

    char* ws = (char*)d_ws;
    // ws layout (bytes):
    //   [0)       fslot int32[32][512]                      65536
    //   [65536)   bpos  int32[32][512]                      65536
    //   [131072)  h ping-pong f32[2dir][2par][64][32][4]   131072
    //   [262144)  c checkpoint f32[2dir][64][4][32]         65536
    //   [327680)  flags: int32[2dir][64] packed               512
    //   [393216)  xg f32[2dir][Tc][1024][32]           Tc*262144
    int*   fslot = (int*)(ws);
    int*   bpos  = (int*)(ws + 65536);
    float* hbuf  = (float*)(ws + 131072);
    float* cbuf  = (float*)(ws + 262144);
    int*   barr  = (int*)(ws + 327680);
    float* xg    = (float*)(ws + 393216);
    (void)in_sizes; (void)n_in; (void)out_size;

    size_t avail = (ws_size > 393216) ? ws_size - 393216 : 0;
    int Tc = 4;
    for (int c = 512; c >= 4; c >>= 1)
        if ((size_t)c * 262144 <= avail) { Tc = c; break; }

    slots_kernel<<<1, 64, 0, stream>>>(fm, bm, fslot, bpos);

    for (int t0 = 0; t0 < T_; t0 += Tc) {
        dim3 g(16, Tc / 4, 2);
        xg_gemm<<<g, 256, 0, stream>>>(inputs, seqlen, emb, Wihf, Wihb,
                                       bihf, bhhf, bihb, bhhb, xg, t0, Tc);
        hipMemsetAsync(barr, 0, 512, stream);   // reset flags for this chunk
        persist_rec<<<128, 512, 0, stream>>>(xg, seqlen, Whhf, Whhb,
                                             fslot, bpos, hbuf, cbuf, barr, out, t0, Tc);
    }
}

// Round 11
// 2086.882 us; speedup vs baseline: 4.7807x; 1.1136x over previous
//
#include <hip/hip_runtime.h>
#include <hip/hip_bf16.h>

#define B_   32
#define T_   512
#define E_   300
#define H_   256
#define OUT_ 256
#define ECH  100    // gemm e-chunk (3 x 100 = 300)
#define GROWP 293   // gbuf row stride; conflict-free (banks 5rg+4bgr cover all 32)

typedef unsigned long long u64;

// ---------------------------------------------------------------------------
// Slot tables, LDS-staged (unchanged).
// ---------------------------------------------------------------------------
__global__ __launch_bounds__(64) void slots_kernel(
    const unsigned char* __restrict__ fm, const unsigned char* __restrict__ bm,
    int* __restrict__ fslot, int* __restrict__ bpos)
{
    __shared__ unsigned char fL[B_ * T_];
    __shared__ unsigned char bL[B_ * T_];
    const int tid = threadIdx.x;

    const unsigned int* fw = (const unsigned int*)fm;
    int cnt = 0;
    for (int i = tid; i < 128; i += 64) {
        unsigned int v = fw[i];
        cnt += ((v & 0xFFu) != 0) + ((v & 0xFF00u) != 0)
             + ((v & 0xFF0000u) != 0) + ((v >> 24) != 0);
    }
#pragma unroll
    for (int off = 32; off; off >>= 1) cnt += __shfl_down(cnt, off, 64);
    bool isbool = __shfl(cnt, 0, 64) > 128;

    if (isbool) {
        for (int i = tid; i < B_ * T_ / 4; i += 64) {
            ((unsigned int*)fL)[i] = ((const unsigned int*)fm)[i];
            ((unsigned int*)bL)[i] = ((const unsigned int*)bm)[i];
        }
    } else {
        const unsigned int* bw = (const unsigned int*)bm;
        for (int i = tid; i < B_ * T_; i += 64) {
            fL[i] = fw[i] != 0;
            bL[i] = bw[i] != 0;
        }
    }
    __syncthreads();

    if (tid < B_) {
        int jf = 0, jb = 0;
        for (int t = 0; t < T_; ++t) {
            bool f = fL[tid * T_ + t] != 0;
            bool g = bL[tid * T_ + t] != 0;
            fslot[tid * T_ + t] = f ? (jf++) : -1;
            bpos [tid * T_ + t] = g ? (OUT_ - 1 - (jb++)) : -1;
        }
    }
}

// ---------------------------------------------------------------------------
// Standalone xg GEMM — fallback only (ws too small for full-T xg buffer).
// ---------------------------------------------------------------------------
__global__ __launch_bounds__(256) void xg_gemm(
    const int* __restrict__ inputs, const int* __restrict__ seqlen,
    const float* __restrict__ emb,
    const float* __restrict__ Wihf, const float* __restrict__ Wihb,
    const float* __restrict__ bihf, const float* __restrict__ bhhf,
    const float* __restrict__ bihb, const float* __restrict__ bhhb,
    float* __restrict__ xg, int t0, int TcMax)
{
    const int tg   = blockIdx.y;
    const int dir  = blockIdx.z;
    const int rblk = blockIdx.x * 64;
    const int tid  = threadIdx.x;

    __shared__ float eL[4][B_][ECH];
    __shared__ int   tokS[4][B_];

    if (tid < 128) {
        int t4 = tid >> 5, b = tid & 31;
        int t = t0 + tg * 4 + t4;
        int L = seqlen[b];
        int tt = t;
        if (dir) tt = (t < L) ? (L - 1 - t) : t;
        tokS[t4][b] = inputs[b * T_ + tt];
    }

    const float* W = dir ? Wihb : Wihf;
    const int b  = tid & 31;
    const int r8 = tid >> 5;

    float acc[4][8];
#pragma unroll
    for (int t4 = 0; t4 < 4; ++t4)
#pragma unroll
        for (int m = 0; m < 8; ++m) acc[t4][m] = 0.f;

    for (int ec = 0; ec < 3; ++ec) {
        __syncthreads();
        for (int idx = tid; idx < 3200; idx += 256) {
            int q  = idx % 25;
            int bb = (idx / 25) & 31;
            int t4 = idx / (25 * 32);
            const float* erow = emb + (size_t)tokS[t4][bb] * E_ + ec * ECH;
            *(float4*)&eL[t4][bb][q * 4] = *(const float4*)(erow + q * 4);
        }
        __syncthreads();

        for (int e4 = 0; e4 < 25; ++e4) {
            float4 w4[8];
#pragma unroll
            for (int m = 0; m < 8; ++m)
                w4[m] = *(const float4*)(W + (size_t)(rblk + r8 + m * 8) * E_
                                         + ec * ECH + e4 * 4);
#pragma unroll
            for (int t4 = 0; t4 < 4; ++t4) {
                float4 h4 = *(const float4*)&eL[t4][b][e4 * 4];
#pragma unroll
                for (int m = 0; m < 8; ++m)
                    acc[t4][m] += h4.x * w4[m].x + h4.y * w4[m].y
                                + h4.z * w4[m].z + h4.w * w4[m].w;
            }
        }
    }

    const float* bi = dir ? bihb : bihf;
    const float* bh = dir ? bhhb : bhhf;
#pragma unroll
    for (int t4 = 0; t4 < 4; ++t4) {
        float* outp = xg + (size_t)(dir * TcMax + tg * 4 + t4) * (1024 * B_);
#pragma unroll
        for (int m = 0; m < 8; ++m) {
            int row = rblk + r8 + m * 8;
            outp[(size_t)row * B_ + b] = acc[t4][m] + bi[row] + bh[row];
        }
    }
}

// ---------------------------------------------------------------------------
// Fused kernel: WGs [0, 128) = recurrence (r9 structure); WGs [128, 256)
// = xg producers (fused mode only). Producers write xg via LLC-bypass stores
// and publish per-(dir, 4t-group) counters; recurrence gates its xg prefetch
// on those counters inside the existing flag poll. Recurrence reads xg via
// bypass loads (own-XCD L2 may hold stale lines from the previous replay).
// ---------------------------------------------------------------------------
__global__ __launch_bounds__(512, 2) void fused_lstm(
    const int* __restrict__ inputs, const int* __restrict__ seqlen,
    const float* __restrict__ emb,
    const float* __restrict__ Wihf, const float* __restrict__ Whhf,
    const float* __restrict__ bihf, const float* __restrict__ bhhf,
    const float* __restrict__ Wihb, const float* __restrict__ Whhb,
    const float* __restrict__ bihb, const float* __restrict__ bhhb,
    const int* __restrict__ fslot, const int* __restrict__ bpos,
    float* __restrict__ hbuf, float* __restrict__ cbuf,
    int* __restrict__ barr, int* __restrict__ xgcnt,
    float* __restrict__ xg, float* __restrict__ out,
    int t0, int Tc, int fused)
{
    const int wg  = blockIdx.x;
    const int tid = threadIdx.x;
    __shared__ __align__(16) float smem[13824];   // 55.3 KB, carved per role

    if (wg >= 128) {
        // ---------------- producer role (fused mode only) ----------------
        float* eL   = smem;                        // [4][32][ECH] = 12800 f
        int*   tokS = (int*)(smem + 12800);        // [4][32]
        const int hw = wg - 128;

        for (int j = hw; j < 2048; j += 128) {     // job: (tg, dir, rblk-pair)
            const int tg  = j >> 4;
            const int dir = (j >> 3) & 1;
            const int rp  = j & 7;
            const int rblk = (rp * 2 + (tid >> 8)) * 64;

            if (tid < 128) {
                int t4 = tid >> 5, b = tid & 31;
                int t = tg * 4 + t4;
                int L = seqlen[b];
                int tt = t;
                if (dir) tt = (t < L) ? (L - 1 - t) : t;
                tokS[t4 * B_ + b] = inputs[b * T_ + tt];
            }

            const float* W  = dir ? Wihb : Wihf;
            const int ltid = tid & 255;
            const int b  = ltid & 31;
            const int r8 = ltid >> 5;

            float acc[4][8];
#pragma unroll
            for (int t4 = 0; t4 < 4; ++t4)
#pragma unroll
                for (int m = 0; m < 8; ++m) acc[t4][m] = 0.f;

            for (int ec = 0; ec < 3; ++ec) {
                __syncthreads();   // tokS ready / eL consumed
                for (int idx = tid; idx < 3200; idx += 512) {
                    int q  = idx % 25;
                    int bb = (idx / 25) & 31;
                    int t4 = idx / (25 * 32);
                    const float* erow = emb + (size_t)tokS[t4 * B_ + bb] * E_ + ec * ECH;
                    *(float4*)&eL[(t4 * B_ + bb) * ECH + q * 4] = *(const float4*)(erow + q * 4);
                }
                __syncthreads();

                for (int e4 = 0; e4 < 25; ++e4) {
                    float4 w4[8];
#pragma unroll
                    for (int m = 0; m < 8; ++m)
                        w4[m] = *(const float4*)(W + (size_t)(rblk + r8 + m * 8) * E_
                                                 + ec * ECH + e4 * 4);
#pragma unroll
                    for (int t4 = 0; t4 < 4; ++t4) {
                        float4 h4 = *(const float4*)&eL[(t4 * B_ + b) * ECH + e4 * 4];
#pragma unroll
                        for (int m = 0; m < 8; ++m)
                            acc[t4][m] += h4.x * w4[m].x + h4.y * w4[m].y
                                        + h4.z * w4[m].z + h4.w * w4[m].w;
                    }
                }
            }

            const float* bi = dir ? bihb : bihf;
            const float* bh = dir ? bhhb : bhhf;
#pragma unroll
            for (int t4 = 0; t4 < 4; ++t4) {
                float* outp = xg + (size_t)(dir * 512 + tg * 4 + t4) * (1024 * B_);
#pragma unroll
                for (int m = 0; m < 8; ++m) {
                    int row = rblk + r8 + m * 8;
                    __hip_atomic_store(&outp[(size_t)row * B_ + b],
                                       acc[t4][m] + bi[row] + bh[row],
                                       __ATOMIC_RELAXED, __HIP_MEMORY_SCOPE_AGENT);
                }
            }
            __syncthreads();   // per-wave vmcnt(0): all bypass stores at LLC
            if (tid == 0)
                __hip_atomic_fetch_add(&xgcnt[dir * 128 + tg], 1,
                                       __ATOMIC_RELAXED, __HIP_MEMORY_SCOPE_AGENT);
        }
        return;
    }

    // ------------------------- recurrence role -------------------------
    float* hP   = smem;                      // 8704 f (34.8 KB)
    float* gbuf = smem + 8704;               // 16*GROWP = 4688 f
    int*   sL   = (int*)(smem + 8704 + 4688);

    const int dir = wg >> 6;
    const int wgd = wg & 63;
    const int u0  = wgd * 4;

    const int rg  = tid & 3;
    const int bgr = (tid >> 2) & 7;
    const int kq  = tid >> 5;

    const float* Whh = dir ? Whhb : Whhf;

    float w[4][16];
#pragma unroll
    for (int r = 0; r < 4; ++r) {
        const float* wr = Whh + (size_t)(rg * H_ + u0 + r) * H_ + kq * 16;
#pragma unroll
        for (int q = 0; q < 4; ++q) {
            float4 v = *(const float4*)(wr + q * 4);
            w[r][q * 4 + 0] = v.x; w[r][q * 4 + 1] = v.y;
            w[r][q * 4 + 2] = v.z; w[r][q * 4 + 3] = v.w;
        }
    }
    if (tid < B_) sL[tid] = seqlen[tid];
    __syncthreads();

    const int ul = (tid >> 5) & 3, bb = tid & 31;
    float c_reg = 0.f;
    if (t0 > 0 && tid < 128)
        c_reg = cbuf[(size_t)(dir * 64 + wgd) * 128 + ul * 32 + bb];

    // gate initial xg group (fused), then load xgv via bypass
    if (fused) {
        if (tid == 0) {
            const int* xc = xgcnt + dir * 128 + (t0 >> 2);
            while (__hip_atomic_load(xc, __ATOMIC_RELAXED,
                                     __HIP_MEMORY_SCOPE_AGENT) < 8)
                __builtin_amdgcn_s_sleep(1);
        }
        __syncthreads();
    }
    float xgv0 = 0.f, xgv1 = 0.f, xgv2 = 0.f, xgv3 = 0.f;
    if (tid < 128) {
        const float* xp = xg + (size_t)(dir * Tc) * 32768 + (u0 + ul) * 32 + bb;
        xgv0 = __hip_atomic_load(xp, __ATOMIC_RELAXED, __HIP_MEMORY_SCOPE_AGENT);
        xgv1 = __hip_atomic_load(xp + 256 * 32, __ATOMIC_RELAXED, __HIP_MEMORY_SCOPE_AGENT);
        xgv2 = __hip_atomic_load(xp + 512 * 32, __ATOMIC_RELAXED, __HIP_MEMORY_SCOPE_AGENT);
        xgv3 = __hip_atomic_load(xp + 768 * 32, __ATOMIC_RELAXED, __HIP_MEMORY_SCOPE_AGENT);
    }

    int* myflag = barr + dir * 64 + wgd;

    for (int tc = 0; tc < Tc; ++tc) {
        const int t = t0 + tc;

        if (tc > 0) {
            if (tid < 64) {
                const int* fp = barr + dir * 64 + tid;
                const int gneed = (fused && tc + 1 < Tc) ? ((t0 + tc + 1) >> 2) : -1;
                const int* xc = xgcnt + dir * 128 + (gneed < 0 ? 0 : gneed);
                for (;;) {
                    bool ok = __hip_atomic_load(fp, __ATOMIC_RELAXED,
                                                __HIP_MEMORY_SCOPE_AGENT) >= tc;
                    if (gneed >= 0 && tid == 0)
                        ok = ok && (__hip_atomic_load(xc, __ATOMIC_RELAXED,
                                                      __HIP_MEMORY_SCOPE_AGENT) >= 8);
                    if (__all(ok)) break;
                    __builtin_amdgcn_s_sleep(1);
                }
            }
            __syncthreads();
        }

        // prefetch next step's xg (validated by the poll above; consumed next iter)
        float xgn0 = 0.f, xgn1 = 0.f, xgn2 = 0.f, xgn3 = 0.f;
        if (tc + 1 < Tc && tid < 128) {
            const float* xp = xg + (size_t)(dir * Tc + tc + 1) * 32768 + (u0 + ul) * 32 + bb;
            xgn0 = __hip_atomic_load(xp, __ATOMIC_RELAXED, __HIP_MEMORY_SCOPE_AGENT);
            xgn1 = __hip_atomic_load(xp + 256 * 32, __ATOMIC_RELAXED, __HIP_MEMORY_SCOPE_AGENT);
            xgn2 = __hip_atomic_load(xp + 512 * 32, __ATOMIC_RELAXED, __HIP_MEMORY_SCOPE_AGENT);
            xgn3 = __hip_atomic_load(xp + 768 * 32, __ATOMIC_RELAXED, __HIP_MEMORY_SCOPE_AGENT);
        }

        // stage h(t-1): LOAD phase then STORE phase (r9 structure)
        u64 hr[8];
        if (t > 0) {
            const u64* hp64 = (const u64*)(hbuf +
                (size_t)(dir * 2 + ((t - 1) & 1)) * (64 * 32 * 4));
#pragma unroll
            for (int i = 0; i < 8; ++i)
                hr[i] = __hip_atomic_load(hp64 + tid + 512 * i, __ATOMIC_RELAXED,
                                          __HIP_MEMORY_SCOPE_AGENT);
#pragma unroll
            for (int i = 0; i < 8; ++i) {
                int g = tid + 512 * i;
                int f4 = g >> 1, jp = g & 1;
                int k4 = f4 >> 5, b = f4 & 31;
                int base = ((k4 >> 2) * 8 + (b >> 2)) * 68 + (k4 & 3) * 16 + (b & 3);
                union { u64 u; float f[2]; } cv; cv.u = hr[i];
                hP[base + 8 * jp]     = cv.f[0];
                hP[base + 8 * jp + 4] = cv.f[1];
            }
        }
        __syncthreads();

        float acc[4][4];
#pragma unroll
        for (int r = 0; r < 4; ++r)
#pragma unroll
            for (int bi = 0; bi < 4; ++bi) acc[r][bi] = 0.f;

        if (t > 0) {
            const float* hblk = &hP[(kq * 8 + bgr) * 68];
#pragma unroll
            for (int kk = 0; kk < 16; ++kk) {
                float4 h4 = *(const float4*)(hblk + kk * 4);
#pragma unroll
                for (int r = 0; r < 4; ++r) {
                    acc[r][0] += w[r][kk] * h4.x;
                    acc[r][1] += w[r][kk] * h4.y;
                    acc[r][2] += w[r][kk] * h4.z;
                    acc[r][3] += w[r][kk] * h4.w;
                }
            }
        }

#pragma unroll
        for (int r = 0; r < 4; ++r)
#pragma unroll
            for (int bi = 0; bi < 4; ++bi)
                acc[r][bi] += __shfl_xor(acc[r][bi], 32, 64);

        if (((tid >> 5) & 1) == 0) {
            const int kq2 = kq >> 1;
#pragma unroll
            for (int r = 0; r < 4; ++r)
#pragma unroll
                for (int bi = 0; bi < 4; ++bi)
                    gbuf[(r * 4 + rg) * GROWP + (bgr * 4 + bi) * 9 + kq2] = acc[r][bi];
        }
        __syncthreads();

        if (tid < 128) {
            const int u = u0 + ul;
            float hnew;
            if (t < sL[bb]) {
                float gi = xgv0, gf = xgv1, gg = xgv2, go = xgv3;
#pragma unroll
                for (int q = 0; q < 8; ++q) {
                    gi += gbuf[(ul * 4 + 0) * GROWP + bb * 9 + q];
                    gf += gbuf[(ul * 4 + 1) * GROWP + bb * 9 + q];
                    gg += gbuf[(ul * 4 + 2) * GROWP + bb * 9 + q];
                    go += gbuf[(ul * 4 + 3) * GROWP + bb * 9 + q];
                }
                float si = 1.f / (1.f + expf(-gi));
                float sf = 1.f / (1.f + expf(-gf));
                float so = 1.f / (1.f + expf(-go));
                c_reg = sf * c_reg + si * tanhf(gg);
                hnew  = so * tanhf(c_reg);
                if (dir == 0) {
                    int j = fslot[bb * T_ + t];
                    if (j >= 0)
                        __hip_atomic_store(&out[((size_t)bb * OUT_ + j) * 512 + u],
                                           hnew, __ATOMIC_RELAXED,
                                           __HIP_MEMORY_SCOPE_AGENT);
                } else {
                    int p = bpos[bb * T_ + t];
                    if (p >= 0)
                        __hip_atomic_store(&out[((size_t)bb * OUT_ + p) * 512 + 256 + u],
                                           hnew, __ATOMIC_RELAXED,
                                           __HIP_MEMORY_SCOPE_AGENT);
                }
            } else {
                hnew = hP[((u >> 4) * 8 + (bb >> 2)) * 68 + (u & 15) * 4 + (bb & 3)];
            }
            float* hn = hbuf + (size_t)(dir * 2 + (t & 1)) * (64 * 32 * 4);
            __hip_atomic_store(&hn[(wgd * 32 + bb) * 4 + ul], hnew,
                               __ATOMIC_RELAXED, __HIP_MEMORY_SCOPE_AGENT);
        }
        xgv0 = xgn0; xgv1 = xgn1; xgv2 = xgn2; xgv3 = xgn3;
        __syncthreads();   // per-wave vmcnt(0): h stores at LLC before flag

        if (tc + 1 < Tc && tid == 0)
            __hip_atomic_store(myflag, tc + 1, __ATOMIC_RELAXED,
                               __HIP_MEMORY_SCOPE_AGENT);
    }

    if (tid < 128)
        cbuf[(size_t)(dir * 64 + wgd) * 128 + ul * 32 + bb] = c_reg;
}

// ---------------------------------------------------------------------------
extern "C" void kernel_launch(void* const* d_in, const int* in_sizes, int n_in,
                              void* d_out, int out_size, void* d_ws, size_t ws_size,
                              hipStream_t stream) {
    const int*           inputs = (const int*)d_in[0];
    const int*           seqlen = (const int*)d_in[1];
    const unsigned char* fm     = (const unsigned char*)d_in[2];
    const unsigned char* bm     = (const unsigned char*)d_in[3];
    // d_in[4] = out_seq_length (== 256, hardcoded)
    const float* emb  = (const float*)d_in[5];
    const float* Wihf = (const float*)d_in[6];
    const float* Whhf = (const float*)d_in[7];
    const float* bihf = (const float*)d_in[8];
    const float* bhhf = (const float*)d_in[9];
    const float* Wihb = (const float*)d_in[10];
    const float* Whhb = (const float*)d_in[11];
    const float* bihb = (const float*)d_in[12];
    const float* bhhb = (const float*)d_in[13];
    float* out = (float*)d_out;

    char* ws = (char*)d_ws;
    // ws layout (bytes):
    //   [0)       fslot int32[32][512]                      65536
    //   [65536)   bpos  int32[32][512]                      65536
    //   [131072)  h ping-pong f32[2dir][2par][64][32][4]   131072
    //   [262144)  c checkpoint f32[2dir][64][4][32]         65536
    //   [327680)  flags int32[2dir][64]                       512
    //   [328192)  xgcnt int32[2dir][128]                     1024
    //   [393216)  xg f32[2dir][Tc][1024][32]           Tc*262144
    int*   fslot = (int*)(ws);
    int*   bpos  = (int*)(ws + 65536);
    float* hbuf  = (float*)(ws + 131072);
    float* cbuf  = (float*)(ws + 262144);
    int*   barr  = (int*)(ws + 327680);
    int*   xgcnt = (int*)(ws + 328192);
    float* xg    = (float*)(ws + 393216);
    (void)in_sizes; (void)n_in; (void)out_size;

    size_t avail = (ws_size > 393216) ? ws_size - 393216 : 0;
    int Tc = 4;
    for (int c = 512; c >= 4; c >>= 1)
        if ((size_t)c * 262144 <= avail) { Tc = c; break; }

    slots_kernel<<<1, 64, 0, stream>>>(fm, bm, fslot, bpos);

    if (Tc == 512) {
        // fused: 128 recurrence WGs + 128 xg-producer WGs, one launch
        (void)hipMemsetAsync(barr, 0, 512 + 1024, stream);
        fused_lstm<<<256, 512, 0, stream>>>(
            inputs, seqlen, emb, Wihf, Whhf, bihf, bhhf,
            Wihb, Whhb, bihb, bhhb, fslot, bpos,
            hbuf, cbuf, barr, xgcnt, xg, out, 0, 512, 1);
    } else {
        // fallback: chunked, separate gemm kernel (r9 structure)
        for (int t0 = 0; t0 < T_; t0 += Tc) {
            dim3 g(16, Tc / 4, 2);
            xg_gemm<<<g, 256, 0, stream>>>(inputs, seqlen, emb, Wihf, Wihb,
                                           bihf, bhhf, bihb, bhhb, xg, t0, Tc);
            (void)hipMemsetAsync(barr, 0, 512 + 1024, stream);
            fused_lstm<<<128, 512, 0, stream>>>(
                inputs, seqlen, emb, Wihf, Whhf, bihf, bhhf,
                Wihb, Whhb, bihb, bhhb, fslot, bpos,
                hbuf, cbuf, barr, xgcnt, xg, out, t0, Tc, 0);
        }
    }
}

// Round 12
// 2038.763 us; speedup vs baseline: 4.8935x; 1.0236x over previous
//
#include <hip/hip_runtime.h>
#include <hip/hip_bf16.h>

#define B_   32
#define T_   512
#define E_   300
#define H_   256
#define OUT_ 256
#define ECH  100    // gemm e-chunk (3 x 100 = 300)
#define GROWP 293   // gbuf row stride; conflict-free (banks 5rg+4bgr cover all 32)

typedef unsigned long long u64;

// ---------------------------------------------------------------------------
// Slot tables, LDS-staged (unchanged).
// ---------------------------------------------------------------------------
__global__ __launch_bounds__(64) void slots_kernel(
    const unsigned char* __restrict__ fm, const unsigned char* __restrict__ bm,
    int* __restrict__ fslot, int* __restrict__ bpos)
{
    __shared__ unsigned char fL[B_ * T_];
    __shared__ unsigned char bL[B_ * T_];
    const int tid = threadIdx.x;

    const unsigned int* fw = (const unsigned int*)fm;
    int cnt = 0;
    for (int i = tid; i < 128; i += 64) {
        unsigned int v = fw[i];
        cnt += ((v & 0xFFu) != 0) + ((v & 0xFF00u) != 0)
             + ((v & 0xFF0000u) != 0) + ((v >> 24) != 0);
    }
#pragma unroll
    for (int off = 32; off; off >>= 1) cnt += __shfl_down(cnt, off, 64);
    bool isbool = __shfl(cnt, 0, 64) > 128;

    if (isbool) {
        for (int i = tid; i < B_ * T_ / 4; i += 64) {
            ((unsigned int*)fL)[i] = ((const unsigned int*)fm)[i];
            ((unsigned int*)bL)[i] = ((const unsigned int*)bm)[i];
        }
    } else {
        const unsigned int* bw = (const unsigned int*)bm;
        for (int i = tid; i < B_ * T_; i += 64) {
            fL[i] = fw[i] != 0;
            bL[i] = bw[i] != 0;
        }
    }
    __syncthreads();

    if (tid < B_) {
        int jf = 0, jb = 0;
        for (int t = 0; t < T_; ++t) {
            bool f = fL[tid * T_ + t] != 0;
            bool g = bL[tid * T_ + t] != 0;
            fslot[tid * T_ + t] = f ? (jf++) : -1;
            bpos [tid * T_ + t] = g ? (OUT_ - 1 - (jb++)) : -1;
        }
    }
}

// ---------------------------------------------------------------------------
// Standalone xg GEMM — fallback only (ws too small for full-T xg buffer).
// ---------------------------------------------------------------------------
__global__ __launch_bounds__(256) void xg_gemm(
    const int* __restrict__ inputs, const int* __restrict__ seqlen,
    const float* __restrict__ emb,
    const float* __restrict__ Wihf, const float* __restrict__ Wihb,
    const float* __restrict__ bihf, const float* __restrict__ bhhf,
    const float* __restrict__ bihb, const float* __restrict__ bhhb,
    float* __restrict__ xg, int t0, int TcMax)
{
    const int tg   = blockIdx.y;
    const int dir  = blockIdx.z;
    const int rblk = blockIdx.x * 64;
    const int tid  = threadIdx.x;

    __shared__ float eL[4][B_][ECH];
    __shared__ int   tokS[4][B_];

    if (tid < 128) {
        int t4 = tid >> 5, b = tid & 31;
        int t = t0 + tg * 4 + t4;
        int L = seqlen[b];
        int tt = t;
        if (dir) tt = (t < L) ? (L - 1 - t) : t;
        tokS[t4][b] = inputs[b * T_ + tt];
    }

    const float* W = dir ? Wihb : Wihf;
    const int b  = tid & 31;
    const int r8 = tid >> 5;

    float acc[4][8];
#pragma unroll
    for (int t4 = 0; t4 < 4; ++t4)
#pragma unroll
        for (int m = 0; m < 8; ++m) acc[t4][m] = 0.f;

    for (int ec = 0; ec < 3; ++ec) {
        __syncthreads();
        for (int idx = tid; idx < 3200; idx += 256) {
            int q  = idx % 25;
            int bb = (idx / 25) & 31;
            int t4 = idx / (25 * 32);
            const float* erow = emb + (size_t)tokS[t4][bb] * E_ + ec * ECH;
            *(float4*)&eL[t4][bb][q * 4] = *(const float4*)(erow + q * 4);
        }
        __syncthreads();

        for (int e4 = 0; e4 < 25; ++e4) {
            float4 w4[8];
#pragma unroll
            for (int m = 0; m < 8; ++m)
                w4[m] = *(const float4*)(W + (size_t)(rblk + r8 + m * 8) * E_
                                         + ec * ECH + e4 * 4);
#pragma unroll
            for (int t4 = 0; t4 < 4; ++t4) {
                float4 h4 = *(const float4*)&eL[t4][b][e4 * 4];
#pragma unroll
                for (int m = 0; m < 8; ++m)
                    acc[t4][m] += h4.x * w4[m].x + h4.y * w4[m].y
                                + h4.z * w4[m].z + h4.w * w4[m].w;
            }
        }
    }

    const float* bi = dir ? bihb : bihf;
    const float* bh = dir ? bhhb : bhhf;
#pragma unroll
    for (int t4 = 0; t4 < 4; ++t4) {
        float* outp = xg + (size_t)(dir * TcMax + tg * 4 + t4) * (1024 * B_);
#pragma unroll
        for (int m = 0; m < 8; ++m) {
            int row = rblk + r8 + m * 8;
            outp[(size_t)row * B_ + b] = acc[t4][m] + bi[row] + bh[row];
        }
    }
}

// ---------------------------------------------------------------------------
// Fused kernel v2. vs r11:
//  (1) h layout [dir][par][wgd][ul*32+b]: publish = 128 consecutive 4B bypass
//      stores (coalesced); load side = 8 u64 bypass loads + 8 ds_write_b64.
//  (2) out scatter stores moved AFTER the flag store (off the drain path).
//  (3) per-wave poll of its own 8 producer flags; no post-poll barrier
//      (own-WG hazards covered by the pre-dot / post-dot / post-epilogue
//      barriers; all own waves passed post-epilogue before any wave polls).
// ---------------------------------------------------------------------------
__global__ __launch_bounds__(512, 2) void fused_lstm(
    const int* __restrict__ inputs, const int* __restrict__ seqlen,
    const float* __restrict__ emb,
    const float* __restrict__ Wihf, const float* __restrict__ Whhf,
    const float* __restrict__ bihf, const float* __restrict__ bhhf,
    const float* __restrict__ Wihb, const float* __restrict__ Whhb,
    const float* __restrict__ bihb, const float* __restrict__ bhhb,
    const int* __restrict__ fslot, const int* __restrict__ bpos,
    float* __restrict__ hbuf, float* __restrict__ cbuf,
    int* __restrict__ barr, int* __restrict__ xgcnt,
    float* __restrict__ xg, float* __restrict__ out,
    int t0, int Tc, int fused)
{
    const int wg  = blockIdx.x;
    const int tid = threadIdx.x;
    __shared__ __align__(16) float smem[13824];   // 55.3 KB, carved per role

    if (wg >= 128) {
        // ---------------- producer role (fused mode only) ----------------
        float* eL   = smem;                        // [4][32][ECH] = 12800 f
        int*   tokS = (int*)(smem + 12800);        // [4][32]
        const int hw = wg - 128;

        for (int j = hw; j < 2048; j += 128) {     // job: (tg, dir, rblk-pair)
            const int tg  = j >> 4;
            const int dir = (j >> 3) & 1;
            const int rp  = j & 7;
            const int rblk = (rp * 2 + (tid >> 8)) * 64;

            if (tid < 128) {
                int t4 = tid >> 5, b = tid & 31;
                int t = tg * 4 + t4;
                int L = seqlen[b];
                int tt = t;
                if (dir) tt = (t < L) ? (L - 1 - t) : t;
                tokS[t4 * B_ + b] = inputs[b * T_ + tt];
            }

            const float* W  = dir ? Wihb : Wihf;
            const int ltid = tid & 255;
            const int b  = ltid & 31;
            const int r8 = ltid >> 5;

            float acc[4][8];
#pragma unroll
            for (int t4 = 0; t4 < 4; ++t4)
#pragma unroll
                for (int m = 0; m < 8; ++m) acc[t4][m] = 0.f;

            for (int ec = 0; ec < 3; ++ec) {
                __syncthreads();   // tokS ready / eL consumed
                for (int idx = tid; idx < 3200; idx += 512) {
                    int q  = idx % 25;
                    int bb = (idx / 25) & 31;
                    int t4 = idx / (25 * 32);
                    const float* erow = emb + (size_t)tokS[t4 * B_ + bb] * E_ + ec * ECH;
                    *(float4*)&eL[(t4 * B_ + bb) * ECH + q * 4] = *(const float4*)(erow + q * 4);
                }
                __syncthreads();

                for (int e4 = 0; e4 < 25; ++e4) {
                    float4 w4[8];
#pragma unroll
                    for (int m = 0; m < 8; ++m)
                        w4[m] = *(const float4*)(W + (size_t)(rblk + r8 + m * 8) * E_
                                                 + ec * ECH + e4 * 4);
#pragma unroll
                    for (int t4 = 0; t4 < 4; ++t4) {
                        float4 h4 = *(const float4*)&eL[(t4 * B_ + b) * ECH + e4 * 4];
#pragma unroll
                        for (int m = 0; m < 8; ++m)
                            acc[t4][m] += h4.x * w4[m].x + h4.y * w4[m].y
                                        + h4.z * w4[m].z + h4.w * w4[m].w;
                    }
                }
            }

            const float* bi = dir ? bihb : bihf;
            const float* bh = dir ? bhhb : bhhf;
#pragma unroll
            for (int t4 = 0; t4 < 4; ++t4) {
                float* outp = xg + (size_t)(dir * 512 + tg * 4 + t4) * (1024 * B_);
#pragma unroll
                for (int m = 0; m < 8; ++m) {
                    int row = rblk + r8 + m * 8;
                    __hip_atomic_store(&outp[(size_t)row * B_ + b],
                                       acc[t4][m] + bi[row] + bh[row],
                                       __ATOMIC_RELAXED, __HIP_MEMORY_SCOPE_AGENT);
                }
            }
            __syncthreads();   // per-wave vmcnt(0): all bypass stores at LLC
            if (tid == 0)
                __hip_atomic_fetch_add(&xgcnt[dir * 128 + tg], 1,
                                       __ATOMIC_RELAXED, __HIP_MEMORY_SCOPE_AGENT);
        }
        return;
    }

    // ------------------------- recurrence role -------------------------
    float* hP   = smem;                      // 8704 f (34.8 KB)
    float* gbuf = smem + 8704;               // 16*GROWP = 4688 f
    int*   sL   = (int*)(smem + 8704 + 4688);

    const int dir = wg >> 6;
    const int wgd = wg & 63;
    const int u0  = wgd * 4;

    const int rg  = tid & 3;
    const int bgr = (tid >> 2) & 7;
    const int kq  = tid >> 5;
    const int wv  = tid >> 6;                // wave id 0..7
    const int lane = tid & 63;

    const float* Whh = dir ? Whhb : Whhf;

    float w[4][16];
#pragma unroll
    for (int r = 0; r < 4; ++r) {
        const float* wr = Whh + (size_t)(rg * H_ + u0 + r) * H_ + kq * 16;
#pragma unroll
        for (int q = 0; q < 4; ++q) {
            float4 v = *(const float4*)(wr + q * 4);
            w[r][q * 4 + 0] = v.x; w[r][q * 4 + 1] = v.y;
            w[r][q * 4 + 2] = v.z; w[r][q * 4 + 3] = v.w;
        }
    }
    if (tid < B_) sL[tid] = seqlen[tid];
    __syncthreads();

    const int ul = (tid >> 5) & 3, bb = tid & 31;
    float c_reg = 0.f;
    if (t0 > 0 && tid < 128)
        c_reg = cbuf[(size_t)(dir * 64 + wgd) * 128 + ul * 32 + bb];

    // gate initial xg group (fused), then load xgv via bypass
    if (fused) {
        if (tid == 0) {
            const int* xc = xgcnt + dir * 128 + (t0 >> 2);
            while (__hip_atomic_load(xc, __ATOMIC_RELAXED,
                                     __HIP_MEMORY_SCOPE_AGENT) < 8)
                __builtin_amdgcn_s_sleep(1);
        }
        __syncthreads();
    }
    float xgv0 = 0.f, xgv1 = 0.f, xgv2 = 0.f, xgv3 = 0.f;
    if (tid < 128) {
        const float* xp = xg + (size_t)(dir * Tc) * 32768 + (u0 + ul) * 32 + bb;
        xgv0 = __hip_atomic_load(xp, __ATOMIC_RELAXED, __HIP_MEMORY_SCOPE_AGENT);
        xgv1 = __hip_atomic_load(xp + 256 * 32, __ATOMIC_RELAXED, __HIP_MEMORY_SCOPE_AGENT);
        xgv2 = __hip_atomic_load(xp + 512 * 32, __ATOMIC_RELAXED, __HIP_MEMORY_SCOPE_AGENT);
        xgv3 = __hip_atomic_load(xp + 768 * 32, __ATOMIC_RELAXED, __HIP_MEMORY_SCOPE_AGENT);
    }

    int* myflag = barr + dir * 64 + wgd;

    for (int tc = 0; tc < Tc; ++tc) {
        const int t = t0 + tc;

        if (tc > 0) {
            // per-wave poll: wave wv's h loads touch producer slices
            // {wv, wv+8, ..., wv+56} only (j = tid+512i -> wgd_src = j>>6).
            const int* fp = barr + dir * 64 + wv + 8 * (lane & 7);
            const int gneed = (fused && wv < 2 && tc + 1 < Tc) ? ((t0 + tc + 1) >> 2) : -1;
            const int* xc = xgcnt + dir * 128 + (gneed < 0 ? 0 : gneed);
            for (;;) {
                bool ok = __hip_atomic_load(fp, __ATOMIC_RELAXED,
                                            __HIP_MEMORY_SCOPE_AGENT) >= tc;
                if (gneed >= 0)
                    ok = ok && (__hip_atomic_load(xc, __ATOMIC_RELAXED,
                                                  __HIP_MEMORY_SCOPE_AGENT) >= 8);
                if (__all(ok)) break;
                __builtin_amdgcn_s_sleep(1);
            }
        }

        // prefetch next step's xg (waves 0-1; validated by their poll)
        float xgn0 = 0.f, xgn1 = 0.f, xgn2 = 0.f, xgn3 = 0.f;
        if (tc + 1 < Tc && tid < 128) {
            const float* xp = xg + (size_t)(dir * Tc + tc + 1) * 32768 + (u0 + ul) * 32 + bb;
            xgn0 = __hip_atomic_load(xp, __ATOMIC_RELAXED, __HIP_MEMORY_SCOPE_AGENT);
            xgn1 = __hip_atomic_load(xp + 256 * 32, __ATOMIC_RELAXED, __HIP_MEMORY_SCOPE_AGENT);
            xgn2 = __hip_atomic_load(xp + 512 * 32, __ATOMIC_RELAXED, __HIP_MEMORY_SCOPE_AGENT);
            xgn3 = __hip_atomic_load(xp + 768 * 32, __ATOMIC_RELAXED, __HIP_MEMORY_SCOPE_AGENT);
        }

        // stage h(t-1): LOAD phase (8 u64 bypass) then STORE phase (8 b64)
        if (t > 0) {
            const u64* hp64 = (const u64*)(hbuf +
                (size_t)(dir * 2 + ((t - 1) & 1)) * 8192);
            u64 hr[8];
#pragma unroll
            for (int i = 0; i < 8; ++i)
                hr[i] = __hip_atomic_load(hp64 + tid + 512 * i, __ATOMIC_RELAXED,
                                          __HIP_MEMORY_SCOPE_AGENT);
#pragma unroll
            for (int i = 0; i < 8; ++i) {
                int j = tid + 512 * i;               // u64 index 0..4095
                int k  = (j >> 6) * 4 + ((j >> 4) & 3);
                int b0 = (j & 15) * 2;
                int addr = ((k >> 4) * 8 + (b0 >> 2)) * 68 + (k & 15) * 4 + (b0 & 3);
                *(u64*)&hP[addr] = hr[i];            // addr even -> 8B aligned
            }
        }
        __syncthreads();

        float acc[4][4];
#pragma unroll
        for (int r = 0; r < 4; ++r)
#pragma unroll
            for (int bi = 0; bi < 4; ++bi) acc[r][bi] = 0.f;

        if (t > 0) {
            const float* hblk = &hP[(kq * 8 + bgr) * 68];
#pragma unroll
            for (int kk = 0; kk < 16; ++kk) {
                float4 h4 = *(const float4*)(hblk + kk * 4);
#pragma unroll
                for (int r = 0; r < 4; ++r) {
                    acc[r][0] += w[r][kk] * h4.x;
                    acc[r][1] += w[r][kk] * h4.y;
                    acc[r][2] += w[r][kk] * h4.z;
                    acc[r][3] += w[r][kk] * h4.w;
                }
            }
        }

#pragma unroll
        for (int r = 0; r < 4; ++r)
#pragma unroll
            for (int bi = 0; bi < 4; ++bi)
                acc[r][bi] += __shfl_xor(acc[r][bi], 32, 64);

        if (((tid >> 5) & 1) == 0) {
            const int kq2 = kq >> 1;
#pragma unroll
            for (int r = 0; r < 4; ++r)
#pragma unroll
                for (int bi = 0; bi < 4; ++bi)
                    gbuf[(r * 4 + rg) * GROWP + (bgr * 4 + bi) * 9 + kq2] = acc[r][bi];
        }
        __syncthreads();

        float hnew = 0.f;
        float* oaddr = nullptr;
        if (tid < 128) {
            const int u = u0 + ul;
            if (t < sL[bb]) {
                float gi = xgv0, gf = xgv1, gg = xgv2, go = xgv3;
#pragma unroll
                for (int q = 0; q < 8; ++q) {
                    gi += gbuf[(ul * 4 + 0) * GROWP + bb * 9 + q];
                    gf += gbuf[(ul * 4 + 1) * GROWP + bb * 9 + q];
                    gg += gbuf[(ul * 4 + 2) * GROWP + bb * 9 + q];
                    go += gbuf[(ul * 4 + 3) * GROWP + bb * 9 + q];
                }
                float si = 1.f / (1.f + expf(-gi));
                float sf = 1.f / (1.f + expf(-gf));
                float so = 1.f / (1.f + expf(-go));
                c_reg = sf * c_reg + si * tanhf(gg);
                hnew  = so * tanhf(c_reg);
                if (dir == 0) {
                    int j = fslot[bb * T_ + t];
                    if (j >= 0) oaddr = &out[((size_t)bb * OUT_ + j) * 512 + u];
                } else {
                    int p = bpos[bb * T_ + t];
                    if (p >= 0) oaddr = &out[((size_t)bb * OUT_ + p) * 512 + 256 + u];
                }
            } else {
                hnew = hP[((u >> 4) * 8 + (bb >> 2)) * 68 + (u & 15) * 4 + (bb & 3)];
            }
            // coalesced publish: word index within slice == tid (ul*32+bb)
            float* hn = hbuf + (size_t)(dir * 2 + (t & 1)) * 8192;
            __hip_atomic_store(&hn[wgd * 128 + tid], hnew,
                               __ATOMIC_RELAXED, __HIP_MEMORY_SCOPE_AGENT);
        }
        xgv0 = xgn0; xgv1 = xgn1; xgv2 = xgn2; xgv3 = xgn3;
        __syncthreads();   // per-wave vmcnt(0): h publish at LLC before flag

        if (tc + 1 < Tc && tid == 0)
            __hip_atomic_store(myflag, tc + 1, __ATOMIC_RELAXED,
                               __HIP_MEMORY_SCOPE_AGENT);
        // out scatter AFTER the flag: off the critical drain path
        if (oaddr)
            __hip_atomic_store(oaddr, hnew, __ATOMIC_RELAXED,
                               __HIP_MEMORY_SCOPE_AGENT);
    }

    if (tid < 128)
        cbuf[(size_t)(dir * 64 + wgd) * 128 + ul * 32 + bb] = c_reg;
}

// ---------------------------------------------------------------------------
extern "C" void kernel_launch(void* const* d_in, const int* in_sizes, int n_in,
                              void* d_out, int out_size, void* d_ws, size_t ws_size,
                              hipStream_t stream) {
    const int*           inputs = (const int*)d_in[0];
    const int*           seqlen = (const int*)d_in[1];
    const unsigned char* fm     = (const unsigned char*)d_in[2];
    const unsigned char* bm     = (const unsigned char*)d_in[3];
    // d_in[4] = out_seq_length (== 256, hardcoded)
    const float* emb  = (const float*)d_in[5];
    const float* Wihf = (const float*)d_in[6];
    const float* Whhf = (const float*)d_in[7];
    const float* bihf = (const float*)d_in[8];
    const float* bhhf = (const float*)d_in[9];
    const float* Wihb = (const float*)d_in[10];
    const float* Whhb = (const float*)d_in[11];
    const float* bihb = (const float*)d_in[12];
    const float* bhhb = (const float*)d_in[13];
    float* out = (float*)d_out;

    char* ws = (char*)d_ws;
    // ws layout (bytes):
    //   [0)       fslot int32[32][512]                      65536
    //   [65536)   bpos  int32[32][512]                      65536
    //   [131072)  h ping-pong f32[2dir][2par][64][128]     131072
    //   [262144)  c checkpoint f32[2dir][64][4][32]         65536
    //   [327680)  flags int32[2dir][64]                       512
    //   [328192)  xgcnt int32[2dir][128]                     1024
    //   [393216)  xg f32[2dir][Tc][1024][32]           Tc*262144
    int*   fslot = (int*)(ws);
    int*   bpos  = (int*)(ws + 65536);
    float* hbuf  = (float*)(ws + 131072);
    float* cbuf  = (float*)(ws + 262144);
    int*   barr  = (int*)(ws + 327680);
    int*   xgcnt = (int*)(ws + 328192);
    float* xg    = (float*)(ws + 393216);
    (void)in_sizes; (void)n_in; (void)out_size;

    size_t avail = (ws_size > 393216) ? ws_size - 393216 : 0;
    int Tc = 4;
    for (int c = 512; c >= 4; c >>= 1)
        if ((size_t)c * 262144 <= avail) { Tc = c; break; }

    slots_kernel<<<1, 64, 0, stream>>>(fm, bm, fslot, bpos);

    if (Tc == 512) {
        // fused: 128 recurrence WGs + 128 xg-producer WGs, one launch
        (void)hipMemsetAsync(barr, 0, 512 + 1024, stream);
        fused_lstm<<<256, 512, 0, stream>>>(
            inputs, seqlen, emb, Wihf, Whhf, bihf, bhhf,
            Wihb, Whhb, bihb, bhhb, fslot, bpos,
            hbuf, cbuf, barr, xgcnt, xg, out, 0, 512, 1);
    } else {
        // fallback: chunked, separate gemm kernel (r9 structure)
        for (int t0 = 0; t0 < T_; t0 += Tc) {
            dim3 g(16, Tc / 4, 2);
            xg_gemm<<<g, 256, 0, stream>>>(inputs, seqlen, emb, Wihf, Wihb,
                                           bihf, bhhf, bihb, bhhb, xg, t0, Tc);
            (void)hipMemsetAsync(barr, 0, 512 + 1024, stream);
            fused_lstm<<<128, 512, 0, stream>>>(
                inputs, seqlen, emb, Wihf, Whhf, bihf, bhhf,
                Wihb, Whhb, bihb, bhhb, fslot, bpos,
                hbuf, cbuf, barr, xgcnt, xg, out, t0, Tc, 0);
        }
    }
}

// Round 13
// 1991.070 us; speedup vs baseline: 5.0107x; 1.0240x over previous
//
#include <hip/hip_runtime.h>
#include <hip/hip_bf16.h>

#define B_   32
#define T_   512
#define E_   300
#define H_   256
#define OUT_ 256
#define ECH  100    // gemm e-chunk (3 x 100 = 300)
#define GROWP 293   // gbuf row stride; conflict-free (banks 5rg+4bgr cover all 32)

typedef unsigned long long u64;

// ---------------------------------------------------------------------------
// Slot tables, LDS-staged (unchanged).
// ---------------------------------------------------------------------------
__global__ __launch_bounds__(64) void slots_kernel(
    const unsigned char* __restrict__ fm, const unsigned char* __restrict__ bm,
    int* __restrict__ fslot, int* __restrict__ bpos)
{
    __shared__ unsigned char fL[B_ * T_];
    __shared__ unsigned char bL[B_ * T_];
    const int tid = threadIdx.x;

    const unsigned int* fw = (const unsigned int*)fm;
    int cnt = 0;
    for (int i = tid; i < 128; i += 64) {
        unsigned int v = fw[i];
        cnt += ((v & 0xFFu) != 0) + ((v & 0xFF00u) != 0)
             + ((v & 0xFF0000u) != 0) + ((v >> 24) != 0);
    }
#pragma unroll
    for (int off = 32; off; off >>= 1) cnt += __shfl_down(cnt, off, 64);
    bool isbool = __shfl(cnt, 0, 64) > 128;

    if (isbool) {
        for (int i = tid; i < B_ * T_ / 4; i += 64) {
            ((unsigned int*)fL)[i] = ((const unsigned int*)fm)[i];
            ((unsigned int*)bL)[i] = ((const unsigned int*)bm)[i];
        }
    } else {
        const unsigned int* bw = (const unsigned int*)bm;
        for (int i = tid; i < B_ * T_; i += 64) {
            fL[i] = fw[i] != 0;
            bL[i] = bw[i] != 0;
        }
    }
    __syncthreads();

    if (tid < B_) {
        int jf = 0, jb = 0;
        for (int t = 0; t < T_; ++t) {
            bool f = fL[tid * T_ + t] != 0;
            bool g = bL[tid * T_ + t] != 0;
            fslot[tid * T_ + t] = f ? (jf++) : -1;
            bpos [tid * T_ + t] = g ? (OUT_ - 1 - (jb++)) : -1;
        }
    }
}

// ---------------------------------------------------------------------------
// Standalone xg GEMM — fallback only (ws too small for full-T xg buffer).
// ---------------------------------------------------------------------------
__global__ __launch_bounds__(256) void xg_gemm(
    const int* __restrict__ inputs, const int* __restrict__ seqlen,
    const float* __restrict__ emb,
    const float* __restrict__ Wihf, const float* __restrict__ Wihb,
    const float* __restrict__ bihf, const float* __restrict__ bhhf,
    const float* __restrict__ bihb, const float* __restrict__ bhhb,
    float* __restrict__ xg, int t0, int TcMax)
{
    const int tg   = blockIdx.y;
    const int dir  = blockIdx.z;
    const int rblk = blockIdx.x * 64;
    const int tid  = threadIdx.x;

    __shared__ float eL[4][B_][ECH];
    __shared__ int   tokS[4][B_];

    if (tid < 128) {
        int t4 = tid >> 5, b = tid & 31;
        int t = t0 + tg * 4 + t4;
        int L = seqlen[b];
        int tt = t;
        if (dir) tt = (t < L) ? (L - 1 - t) : t;
        tokS[t4][b] = inputs[b * T_ + tt];
    }

    const float* W = dir ? Wihb : Wihf;
    const int b  = tid & 31;
    const int r8 = tid >> 5;

    float acc[4][8];
#pragma unroll
    for (int t4 = 0; t4 < 4; ++t4)
#pragma unroll
        for (int m = 0; m < 8; ++m) acc[t4][m] = 0.f;

    for (int ec = 0; ec < 3; ++ec) {
        __syncthreads();
        for (int idx = tid; idx < 3200; idx += 256) {
            int q  = idx % 25;
            int bb = (idx / 25) & 31;
            int t4 = idx / (25 * 32);
            const float* erow = emb + (size_t)tokS[t4][bb] * E_ + ec * ECH;
            *(float4*)&eL[t4][bb][q * 4] = *(const float4*)(erow + q * 4);
        }
        __syncthreads();

        for (int e4 = 0; e4 < 25; ++e4) {
            float4 w4[8];
#pragma unroll
            for (int m = 0; m < 8; ++m)
                w4[m] = *(const float4*)(W + (size_t)(rblk + r8 + m * 8) * E_
                                         + ec * ECH + e4 * 4);
#pragma unroll
            for (int t4 = 0; t4 < 4; ++t4) {
                float4 h4 = *(const float4*)&eL[t4][b][e4 * 4];
#pragma unroll
                for (int m = 0; m < 8; ++m)
                    acc[t4][m] += h4.x * w4[m].x + h4.y * w4[m].y
                                + h4.z * w4[m].z + h4.w * w4[m].w;
            }
        }
    }

    const float* bi = dir ? bihb : bihf;
    const float* bh = dir ? bhhb : bhhf;
#pragma unroll
    for (int t4 = 0; t4 < 4; ++t4) {
        float* outp = xg + (size_t)(dir * TcMax + tg * 4 + t4) * (1024 * B_);
#pragma unroll
        for (int m = 0; m < 8; ++m) {
            int row = rblk + r8 + m * 8;
            outp[(size_t)row * B_ + b] = acc[t4][m] + bi[row] + bh[row];
        }
    }
}

// ---------------------------------------------------------------------------
// Fused kernel v3: TAG-IN-DATA h exchange.
// h published as u64 packets {hi = tag (t+1), lo = f32 bits} via bypass
// stores; consumers load packets and validate tags in-register -> flag
// system deleted, discovery and data are ONE LLC trip. Ping-pong + tags
// make overwrite race-free (a WG at t+1 proves everyone consumed t-1).
// Tag t+1 >= 1 != memset-0 -> replay-safe. xg prefetch 2 steps ahead,
// xgcnt checked non-blockingly under the dot.
// ---------------------------------------------------------------------------
__global__ __launch_bounds__(512, 2) void fused_lstm(
    const int* __restrict__ inputs, const int* __restrict__ seqlen,
    const float* __restrict__ emb,
    const float* __restrict__ Wihf, const float* __restrict__ Whhf,
    const float* __restrict__ bihf, const float* __restrict__ bhhf,
    const float* __restrict__ Wihb, const float* __restrict__ Whhb,
    const float* __restrict__ bihb, const float* __restrict__ bhhb,
    const int* __restrict__ fslot, const int* __restrict__ bpos,
    u64* __restrict__ hbuf, float* __restrict__ cbuf,
    int* __restrict__ xgcnt, float* __restrict__ xg, float* __restrict__ out,
    int t0, int Tc, int fused)
{
    const int wg  = blockIdx.x;
    const int tid = threadIdx.x;
    __shared__ __align__(16) float smem[13824];   // 55.3 KB, carved per role

    if (wg >= 128) {
        // ---------------- producer role (fused mode only) ----------------
        float* eL   = smem;                        // [4][32][ECH] = 12800 f
        int*   tokS = (int*)(smem + 12800);        // [4][32]
        const int hw = wg - 128;

        for (int j = hw; j < 2048; j += 128) {     // job: (tg, dir, rblk-pair)
            const int tg  = j >> 4;
            const int dir = (j >> 3) & 1;
            const int rp  = j & 7;
            const int rblk = (rp * 2 + (tid >> 8)) * 64;

            if (tid < 128) {
                int t4 = tid >> 5, b = tid & 31;
                int t = tg * 4 + t4;
                int L = seqlen[b];
                int tt = t;
                if (dir) tt = (t < L) ? (L - 1 - t) : t;
                tokS[t4 * B_ + b] = inputs[b * T_ + tt];
            }

            const float* W  = dir ? Wihb : Wihf;
            const int ltid = tid & 255;
            const int b  = ltid & 31;
            const int r8 = ltid >> 5;

            float acc[4][8];
#pragma unroll
            for (int t4 = 0; t4 < 4; ++t4)
#pragma unroll
                for (int m = 0; m < 8; ++m) acc[t4][m] = 0.f;

            for (int ec = 0; ec < 3; ++ec) {
                __syncthreads();   // tokS ready / eL consumed
                for (int idx = tid; idx < 3200; idx += 512) {
                    int q  = idx % 25;
                    int bb = (idx / 25) & 31;
                    int t4 = idx / (25 * 32);
                    const float* erow = emb + (size_t)tokS[t4 * B_ + bb] * E_ + ec * ECH;
                    *(float4*)&eL[(t4 * B_ + bb) * ECH + q * 4] = *(const float4*)(erow + q * 4);
                }
                __syncthreads();

                for (int e4 = 0; e4 < 25; ++e4) {
                    float4 w4[8];
#pragma unroll
                    for (int m = 0; m < 8; ++m)
                        w4[m] = *(const float4*)(W + (size_t)(rblk + r8 + m * 8) * E_
                                                 + ec * ECH + e4 * 4);
#pragma unroll
                    for (int t4 = 0; t4 < 4; ++t4) {
                        float4 h4 = *(const float4*)&eL[(t4 * B_ + b) * ECH + e4 * 4];
#pragma unroll
                        for (int m = 0; m < 8; ++m)
                            acc[t4][m] += h4.x * w4[m].x + h4.y * w4[m].y
                                        + h4.z * w4[m].z + h4.w * w4[m].w;
                    }
                }
            }

            const float* bi = dir ? bihb : bihf;
            const float* bh = dir ? bhhb : bhhf;
#pragma unroll
            for (int t4 = 0; t4 < 4; ++t4) {
                float* outp = xg + (size_t)(dir * 512 + tg * 4 + t4) * (1024 * B_);
#pragma unroll
                for (int m = 0; m < 8; ++m) {
                    int row = rblk + r8 + m * 8;
                    __hip_atomic_store(&outp[(size_t)row * B_ + b],
                                       acc[t4][m] + bi[row] + bh[row],
                                       __ATOMIC_RELAXED, __HIP_MEMORY_SCOPE_AGENT);
                }
            }
            __syncthreads();   // per-wave vmcnt(0): all bypass stores at LLC
            if (tid == 0)
                __hip_atomic_fetch_add(&xgcnt[dir * 128 + tg], 1,
                                       __ATOMIC_RELAXED, __HIP_MEMORY_SCOPE_AGENT);
        }
        return;
    }

    // ------------------------- recurrence role -------------------------
    float* hP   = smem;                      // 8704 f (34.8 KB)
    float* gbuf = smem + 8704;               // 16*GROWP = 4688 f
    int*   sL   = (int*)(smem + 8704 + 4688);

    const int dir = wg >> 6;
    const int wgd = wg & 63;
    const int u0  = wgd * 4;

    const int rg  = tid & 3;
    const int bgr = (tid >> 2) & 7;
    const int kq  = tid >> 5;

    const float* Whh = dir ? Whhb : Whhf;

    float w[4][16];
#pragma unroll
    for (int r = 0; r < 4; ++r) {
        const float* wr = Whh + (size_t)(rg * H_ + u0 + r) * H_ + kq * 16;
#pragma unroll
        for (int q = 0; q < 4; ++q) {
            float4 v = *(const float4*)(wr + q * 4);
            w[r][q * 4 + 0] = v.x; w[r][q * 4 + 1] = v.y;
            w[r][q * 4 + 2] = v.z; w[r][q * 4 + 3] = v.w;
        }
    }
    if (tid < B_) sL[tid] = seqlen[tid];
    __syncthreads();

    const int ul = (tid >> 5) & 3, bb = tid & 31;
    float c_reg = 0.f;
    if (t0 > 0 && tid < 128)
        c_reg = cbuf[(size_t)(dir * 64 + wgd) * 128 + ul * 32 + bb];

    // initial xg: gate group t0>>2 (fused), then load xg(t0), xg(t0+1)
    if (fused) {
        if (tid == 0) {
            const int* xc = xgcnt + dir * 128 + (t0 >> 2);
            while (__hip_atomic_load(xc, __ATOMIC_RELAXED,
                                     __HIP_MEMORY_SCOPE_AGENT) < 8)
                __builtin_amdgcn_s_sleep(1);
        }
        __syncthreads();
    }
    float xv0 = 0.f, xv1 = 0.f, xv2 = 0.f, xv3 = 0.f;   // xg(t)
    float ya0 = 0.f, ya1 = 0.f, ya2 = 0.f, ya3 = 0.f;   // xg(t+1)
    if (tid < 128) {
        const float* xp = xg + (size_t)(dir * Tc) * 32768 + (u0 + ul) * 32 + bb;
        xv0 = __hip_atomic_load(xp,         __ATOMIC_RELAXED, __HIP_MEMORY_SCOPE_AGENT);
        xv1 = __hip_atomic_load(xp +  8192, __ATOMIC_RELAXED, __HIP_MEMORY_SCOPE_AGENT);
        xv2 = __hip_atomic_load(xp + 16384, __ATOMIC_RELAXED, __HIP_MEMORY_SCOPE_AGENT);
        xv3 = __hip_atomic_load(xp + 24576, __ATOMIC_RELAXED, __HIP_MEMORY_SCOPE_AGENT);
        if (Tc > 1) {
            const float* xq = xp + 32768;
            ya0 = __hip_atomic_load(xq,         __ATOMIC_RELAXED, __HIP_MEMORY_SCOPE_AGENT);
            ya1 = __hip_atomic_load(xq +  8192, __ATOMIC_RELAXED, __HIP_MEMORY_SCOPE_AGENT);
            ya2 = __hip_atomic_load(xq + 16384, __ATOMIC_RELAXED, __HIP_MEMORY_SCOPE_AGENT);
            ya3 = __hip_atomic_load(xq + 24576, __ATOMIC_RELAXED, __HIP_MEMORY_SCOPE_AGENT);
        }
    }

    for (int tc = 0; tc < Tc; ++tc) {
        const int t = t0 + tc;

        // [A] h(t-1): load packets, validate tags in-register, retry if stale.
        if (t > 0) {
            const u64* hp = hbuf + (size_t)(dir * 2 + ((t - 1) & 1)) * 8192;
            u64 hr[16];
            for (;;) {
#pragma unroll
                for (int i = 0; i < 16; ++i)
                    hr[i] = __hip_atomic_load(hp + tid + 512 * i, __ATOMIC_RELAXED,
                                              __HIP_MEMORY_SCOPE_AGENT);
                bool ok = true;
#pragma unroll
                for (int i = 0; i < 16; ++i)
                    ok &= ((unsigned)(hr[i] >> 32) == (unsigned)t);
                if (__all(ok)) break;
                __builtin_amdgcn_s_sleep(1);
            }
#pragma unroll
            for (int i = 0; i < 16; ++i) {
                int wdx = tid + 512 * i;                     // word index 0..8191
                int k = ((wdx >> 7) << 2) | ((wdx >> 5) & 3); // unit
                int b = wdx & 31;                             // batch
                hP[((k >> 4) * 8 + (b >> 2)) * 68 + (k & 15) * 4 + (b & 3)] =
                    __uint_as_float((unsigned)hr[i]);
            }
        }
        __syncthreads();

        // non-blocking xgcnt peek for t+2 (waitcnt lands under the dot)
        int cnt = 8;
        if (fused && tc + 2 < Tc && tid < 128)
            cnt = __hip_atomic_load(xgcnt + dir * 128 + ((t0 + tc + 2) >> 2),
                                    __ATOMIC_RELAXED, __HIP_MEMORY_SCOPE_AGENT);

        // [B] dot (W from registers, h from conflict-free hP blocks)
        float acc[4][4];
#pragma unroll
        for (int r = 0; r < 4; ++r)
#pragma unroll
            for (int bi = 0; bi < 4; ++bi) acc[r][bi] = 0.f;

        if (t > 0) {
            const float* hblk = &hP[(kq * 8 + bgr) * 68];
#pragma unroll
            for (int kk = 0; kk < 16; ++kk) {
                float4 h4 = *(const float4*)(hblk + kk * 4);
#pragma unroll
                for (int r = 0; r < 4; ++r) {
                    acc[r][0] += w[r][kk] * h4.x;
                    acc[r][1] += w[r][kk] * h4.y;
                    acc[r][2] += w[r][kk] * h4.z;
                    acc[r][3] += w[r][kk] * h4.w;
                }
            }
        }

#pragma unroll
        for (int r = 0; r < 4; ++r)
#pragma unroll
            for (int bi = 0; bi < 4; ++bi)
                acc[r][bi] += __shfl_xor(acc[r][bi], 32, 64);

        if (((tid >> 5) & 1) == 0) {
            const int kq2 = kq >> 1;
#pragma unroll
            for (int r = 0; r < 4; ++r)
#pragma unroll
                for (int bi = 0; bi < 4; ++bi)
                    gbuf[(r * 4 + rg) * GROWP + (bgr * 4 + bi) * 9 + kq2] = acc[r][bi];
        }
        __syncthreads();

        // [C] epilogue + packet publish (tid<128)
        float hnew = 0.f;
        float* oaddr = nullptr;
        if (tid < 128) {
            const int u = u0 + ul;
            if (t < sL[bb]) {
                float gi = xv0, gf = xv1, gg = xv2, go = xv3;
#pragma unroll
                for (int q = 0; q < 8; ++q) {
                    gi += gbuf[(ul * 4 + 0) * GROWP + bb * 9 + q];
                    gf += gbuf[(ul * 4 + 1) * GROWP + bb * 9 + q];
                    gg += gbuf[(ul * 4 + 2) * GROWP + bb * 9 + q];
                    go += gbuf[(ul * 4 + 3) * GROWP + bb * 9 + q];
                }
                float si = 1.f / (1.f + expf(-gi));
                float sf = 1.f / (1.f + expf(-gf));
                float so = 1.f / (1.f + expf(-go));
                c_reg = sf * c_reg + si * tanhf(gg);
                hnew  = so * tanhf(c_reg);
                if (dir == 0) {
                    int j = fslot[bb * T_ + t];
                    if (j >= 0) oaddr = &out[((size_t)bb * OUT_ + j) * 512 + u];
                } else {
                    int p = bpos[bb * T_ + t];
                    if (p >= 0) oaddr = &out[((size_t)bb * OUT_ + p) * 512 + 256 + u];
                }
            } else {
                hnew = hP[((u >> 4) * 8 + (bb >> 2)) * 68 + (u & 15) * 4 + (bb & 3)];
            }
            // self-validating packet: {tag = t+1, value}; coalesced 1 KB
            u64 pkt = ((u64)(unsigned)(t + 1) << 32) | (u64)__float_as_uint(hnew);
            u64* hn = hbuf + (size_t)(dir * 2 + (t & 1)) * 8192;
            __hip_atomic_store(&hn[wgd * 128 + tid], pkt,
                               __ATOMIC_RELAXED, __HIP_MEMORY_SCOPE_AGENT);
        }
        __syncthreads();   // protect hP/gbuf before next iteration's writes

        // [D] off-critical tail: xg(t+2) load (+rare gate), out scatter
        float z0 = 0.f, z1 = 0.f, z2 = 0.f, z3 = 0.f;
        if (tc + 2 < Tc && tid < 128) {
            if (fused && cnt < 8) {
                const int* xc = xgcnt + dir * 128 + ((t0 + tc + 2) >> 2);
                while (__hip_atomic_load(xc, __ATOMIC_RELAXED,
                                         __HIP_MEMORY_SCOPE_AGENT) < 8)
                    __builtin_amdgcn_s_sleep(1);
            }
            const float* xp = xg + (size_t)(dir * Tc + tc + 2) * 32768 + (u0 + ul) * 32 + bb;
            z0 = __hip_atomic_load(xp,         __ATOMIC_RELAXED, __HIP_MEMORY_SCOPE_AGENT);
            z1 = __hip_atomic_load(xp +  8192, __ATOMIC_RELAXED, __HIP_MEMORY_SCOPE_AGENT);
            z2 = __hip_atomic_load(xp + 16384, __ATOMIC_RELAXED, __HIP_MEMORY_SCOPE_AGENT);
            z3 = __hip_atomic_load(xp + 24576, __ATOMIC_RELAXED, __HIP_MEMORY_SCOPE_AGENT);
        }
        if (oaddr)
            __hip_atomic_store(oaddr, hnew, __ATOMIC_RELAXED,
                               __HIP_MEMORY_SCOPE_AGENT);
        xv0 = ya0; xv1 = ya1; xv2 = ya2; xv3 = ya3;
        ya0 = z0;  ya1 = z1;  ya2 = z2;  ya3 = z3;
    }

    if (tid < 128)
        cbuf[(size_t)(dir * 64 + wgd) * 128 + ul * 32 + bb] = c_reg;
}

// ---------------------------------------------------------------------------
extern "C" void kernel_launch(void* const* d_in, const int* in_sizes, int n_in,
                              void* d_out, int out_size, void* d_ws, size_t ws_size,
                              hipStream_t stream) {
    const int*           inputs = (const int*)d_in[0];
    const int*           seqlen = (const int*)d_in[1];
    const unsigned char* fm     = (const unsigned char*)d_in[2];
    const unsigned char* bm     = (const unsigned char*)d_in[3];
    // d_in[4] = out_seq_length (== 256, hardcoded)
    const float* emb  = (const float*)d_in[5];
    const float* Wihf = (const float*)d_in[6];
    const float* Whhf = (const float*)d_in[7];
    const float* bihf = (const float*)d_in[8];
    const float* bhhf = (const float*)d_in[9];
    const float* Wihb = (const float*)d_in[10];
    const float* Whhb = (const float*)d_in[11];
    const float* bihb = (const float*)d_in[12];
    const float* bhhb = (const float*)d_in[13];
    float* out = (float*)d_out;

    char* ws = (char*)d_ws;
    // ws layout (bytes):
    //   [0)       fslot int32[32][512]                       65536
    //   [65536)   bpos  int32[32][512]                       65536
    //   [131072)  h packets u64[2dir][2par][8192]           262144
    //   [393216)  c checkpoint f32[2dir][64][4][32]          65536
    //   [458752)  xgcnt int32[2dir][128]                      1024
    //   [460800)  xg f32[2dir][Tc][1024][32]            Tc*262144
    int*   fslot = (int*)(ws);
    int*   bpos  = (int*)(ws + 65536);
    u64*   hbuf  = (u64*)(ws + 131072);
    float* cbuf  = (float*)(ws + 393216);
    int*   xgcnt = (int*)(ws + 458752);
    float* xg    = (float*)(ws + 460800);
    (void)in_sizes; (void)n_in; (void)out_size;

    size_t avail = (ws_size > 460800) ? ws_size - 460800 : 0;
    int Tc = 4;
    for (int c = 512; c >= 4; c >>= 1)
        if ((size_t)c * 262144 <= avail) { Tc = c; break; }

    // zero packet tags + xg counters every call (replay-safe: tag 0 is
    // never a valid expected tag since published tags are t+1 >= 1)
    (void)hipMemsetAsync(ws + 131072, 0, 262144, stream);
    (void)hipMemsetAsync(ws + 458752, 0, 1024, stream);
    slots_kernel<<<1, 64, 0, stream>>>(fm, bm, fslot, bpos);

    if (Tc == 512) {
        // fused: 128 recurrence WGs + 128 xg-producer WGs, one launch
        fused_lstm<<<256, 512, 0, stream>>>(
            inputs, seqlen, emb, Wihf, Whhf, bihf, bhhf,
            Wihb, Whhb, bihb, bhhb, fslot, bpos,
            hbuf, cbuf, xgcnt, xg, out, 0, 512, 1);
    } else {
        // fallback: chunked, separate gemm kernel (tags use global t, so
        // they remain consistent across chunk launches)
        for (int t0 = 0; t0 < T_; t0 += Tc) {
            dim3 g(16, Tc / 4, 2);
            xg_gemm<<<g, 256, 0, stream>>>(inputs, seqlen, emb, Wihf, Wihb,
                                           bihf, bhhf, bihb, bhhb, xg, t0, Tc);
            fused_lstm<<<128, 512, 0, stream>>>(
                inputs, seqlen, emb, Wihf, Whhf, bihf, bhhf,
                Wihb, Whhb, bihb, bhhb, fslot, bpos,
                hbuf, cbuf, xgcnt, xg, out, t0, Tc, 0);
        }
    }
}